// Round 2
// baseline (2465.130 us; speedup 1.0000x reference)
//
#include <hip/hip_runtime.h>

// ===== Problem constants =====
constexpr int L_TXT = 256, L_IMG = 2048, SEQ = 2304;
constexpr int DM = 2048, NH = 16, DH = 128;

typedef __attribute__((ext_vector_type(8))) __bf16 bf16x8;
typedef __attribute__((ext_vector_type(4))) float f32x4;

// Runtime dtype flag: 0 = fp32 storage, 1 = bf16 storage. Detected from
// rope_cos[0][0]==1.0f (fp32 -> low u16 is 0x0000; bf16 -> 0x3F80).
__device__ __forceinline__ float ldin(const void* p, size_t i, int bf) {
  return bf ? (float)((const __bf16*)p)[i] : ((const float*)p)[i];
}

// slots: 0:h 1:e 2:q_txt 3:q_img 4:k_txt 5:k_img 6:v_txt 7:v_img 8:attn_out; int flag at byte 48
__device__ __forceinline__ float slot_scale(const unsigned* s) {
  return fmaxf(__uint_as_float(*s) / 127.0f, 1e-8f);
}
__device__ __forceinline__ float qclamp(float x, float sc) {
  float q = rintf(x / sc);                 // RNE, matches jnp.round
  return fminf(fmaxf(q, -127.0f), 127.0f);
}
__device__ __forceinline__ float block_allmax(float v) {
  #pragma unroll
  for (int off = 32; off > 0; off >>= 1) v = fmaxf(v, __shfl_xor(v, off));
  __shared__ float sm[4];
  __syncthreads();
  if ((threadIdx.x & 63) == 0) sm[threadIdx.x >> 6] = v;
  __syncthreads();
  return fmaxf(fmaxf(sm[0], sm[1]), fmaxf(sm[2], sm[3]));
}

__global__ void detect_k(const void* cosp, int* flag) {
  if (threadIdx.x == 0) *flag = (((const unsigned short*)cosp)[0] != 0) ? 1 : 0;
}

// ===== Per-row weight scales (quantization itself fused into GEMM staging) =====
struct Ptrs8 { const void* p[8]; };
__global__ void weight_scales_k(Ptrs8 win, float* __restrict__ scales, const int* __restrict__ flagp) {
  const int bf = *flagp;
  int row = blockIdx.x, mat = blockIdx.y, t = threadIdx.x;
  const void* w = win.p[mat];
  size_t base = (size_t)row * DM;
  float m = 0.f;
  for (int c = t; c < DM; c += 256) m = fmaxf(m, fabsf(ldin(w, base + c, bf)));
  m = block_allmax(m);
  if (t == 0) scales[mat * DM + row] = fmaxf(m / 127.0f, 1e-8f);
}

// ===== Global absmax reductions =====
__global__ void absmax_in_k(const void* __restrict__ x, int n, unsigned* slot, const int* __restrict__ flagp) {
  const int bf = *flagp;
  int i = blockIdx.x * 256 + threadIdx.x, stride = gridDim.x * 256;
  float m = 0.f;
  for (; i < n; i += stride) m = fmaxf(m, fabsf(ldin(x, i, bf)));
  m = block_allmax(m);
  if (threadIdx.x == 0) atomicMax(slot, __float_as_uint(m));
}
__global__ void absmax_f32_k(const float* __restrict__ x, int n, unsigned* slot) {
  int i = blockIdx.x * 256 + threadIdx.x, stride = gridDim.x * 256;
  float m = 0.f;
  for (; i < n; i += stride) m = fmaxf(m, fabsf(x[i]));
  m = block_allmax(m);
  if (threadIdx.x == 0) atomicMax(slot, __float_as_uint(m));
}
// v tensor [NH][SEQ][DH]: txt rows (s<256) and img rows have separate scales
__global__ void absmax_v_k(const float* __restrict__ x, unsigned* st, unsigned* si) {
  int i = blockIdx.x * 256 + threadIdx.x, stride = gridDim.x * 256;
  const int n = NH * SEQ * DH;
  float mt = 0.f, mg = 0.f;
  for (; i < n; i += stride) {
    float a = fabsf(x[i]);
    int s = (i >> 7) % SEQ;
    if (s < L_TXT) mt = fmaxf(mt, a); else mg = fmaxf(mg, a);
  }
  mt = block_allmax(mt);
  mg = block_allmax(mg);
  if (threadIdx.x == 0) { atomicMax(st, __float_as_uint(mt)); atomicMax(si, __float_as_uint(mg)); }
}

// ===== Quantize to INT-grid bf16 (scale applied in GEMM epilogue) =====
__global__ void quant_int_in_k(const void* __restrict__ x, int n, const unsigned* __restrict__ slot,
                               __bf16* __restrict__ out, const int* __restrict__ flagp) {
  const int bf = *flagp;
  int i = blockIdx.x * 256 + threadIdx.x;
  if (i >= n) return;
  float sc = slot_scale(slot);
  out[i] = (__bf16)qclamp(ldin(x, i, bf), sc);
}
__global__ void quant_int_f32_k(const float* __restrict__ x, int n,
                                const unsigned* __restrict__ slot, __bf16* __restrict__ out) {
  int i = blockIdx.x * 256 + threadIdx.x;
  if (i >= n) return;
  float sc = slot_scale(slot);
  out[i] = (__bf16)qclamp(x[i], sc);
}

// ===== RMSNorm in-place on [NH][SEQ][DH] fp32 + per-range absmax =====
__global__ void rmsnorm_absmax_k(float* __restrict__ x, const void* __restrict__ w_img,
                                 const void* __restrict__ w_txt,
                                 unsigned* slot_txt, unsigned* slot_img, const int* __restrict__ flagp) {
  const int bf = *flagp;
  int t = threadIdx.x, lane = t & 63, wave = t >> 6;
  int row = blockIdx.x * 4 + wave;   // h*SEQ + s
  int s = row % SEQ;
  float* p = x + (size_t)row * DH;
  float v0 = p[lane], v1 = p[lane + 64];
  float ss = v0 * v0 + v1 * v1;
  #pragma unroll
  for (int off = 32; off > 0; off >>= 1) ss += __shfl_xor(ss, off);
  float r = rsqrtf(ss * (1.0f / 128.0f) + 1e-6f);
  const void* wn = (s < L_TXT) ? w_txt : w_img;
  float y0 = v0 * r * ldin(wn, lane, bf);
  float y1 = v1 * r * ldin(wn, lane + 64, bf);
  p[lane] = y0; p[lane + 64] = y1;
  float am = fmaxf(fabsf(y0), fabsf(y1));
  #pragma unroll
  for (int off = 32; off > 0; off >>= 1) am = fmaxf(am, __shfl_xor(am, off));
  if (lane == 0) atomicMax(s < L_TXT ? slot_txt : slot_img, __float_as_uint(am));
}

// ===== quantize (dequantized value) + RoPE + cast bf16, per pair =====
__global__ void quant_rope_k(const float* __restrict__ x, const void* __restrict__ cosb,
                             const void* __restrict__ sinb, const unsigned* slot_txt,
                             const unsigned* slot_img, __bf16* __restrict__ out,
                             const int* __restrict__ flagp) {
  const int bf = *flagp;
  int i = blockIdx.x * 256 + threadIdx.x;  // pair index over NH*SEQ*64
  int pr = i & 63;
  int s = (i >> 6) % SEQ;
  size_t base = (size_t)(i >> 6) * DH + pr * 2;
  float sc = slot_scale(s < L_TXT ? slot_txt : slot_img);
  float x0 = x[base], x1 = x[base + 1];
  float q0 = qclamp(x0, sc) * sc;
  float q1 = qclamp(x1, sc) * sc;
  float c0 = ldin(cosb, s * DH + 2 * pr, bf), c1 = ldin(cosb, s * DH + 2 * pr + 1, bf);
  float s0 = ldin(sinb, s * DH + 2 * pr, bf), s1 = ldin(sinb, s * DH + 2 * pr + 1, bf);
  out[base]     = (__bf16)(q0 * c0 - q1 * s0);
  out[base + 1] = (__bf16)(q1 * c1 + q0 * s1);
}

// ===== V: quantize (dequantized) + transpose [NH][SEQ][DH] -> [NH][DH][SEQ] =====
__global__ void quant_transpose_v_k(const float* __restrict__ v, const unsigned* st,
                                    const unsigned* si, __bf16* __restrict__ vt) {
  __shared__ float tile[64][65];
  int t = threadIdx.x;
  int s0 = blockIdx.x * 64, d0 = blockIdx.y * 64, h = blockIdx.z;
  #pragma unroll
  for (int i = 0; i < 16; i++) {
    int r = i * 4 + (t >> 6), c = t & 63;
    tile[r][c] = v[((size_t)(h * SEQ) + s0 + r) * DH + d0 + c];
  }
  __syncthreads();
  float sc = slot_scale(s0 < L_TXT ? st : si);
  #pragma unroll
  for (int i = 0; i < 16; i++) {
    int d = i * 4 + (t >> 6), s = t & 63;
    float q = qclamp(tile[s][d], sc) * sc;
    vt[((size_t)(h * DH) + d0 + d) * SEQ + s0 + s] = (__bf16)q;
  }
}

// ===== GEMM: C[m,n] = ascale*wscale[n]*(Aq @ Wq^T) + bias[n] =====
// A: Mx2048 int-bf16 (internal). W: raw input (fp32 or bf16), quantized on the
// fly during LDS staging using per-row scales. 128x128 tile, BK=64, 4 waves.
// MODE 0: fp32 head-split out [(n>>7)][off+m][n&127]; MODE 1: out rows at (m+off)*2048+n, dtype per flag
template<int MODE>
__global__ __launch_bounds__(256, 2)
void gemm_bt(const __bf16* __restrict__ A, const void* __restrict__ W,
             const float* __restrict__ wscale, const unsigned* __restrict__ aslot,
             const void* __restrict__ bias, void* __restrict__ outp,
             const int* __restrict__ flagp, int off) {
  const int bf = *flagp;
  constexpr int K = 2048;
  __shared__ __bf16 As[128][72];   // +8 pad
  __shared__ __bf16 Ws[128][72];
  int t = threadIdx.x, lane = t & 63, wave = t >> 6;
  int l15 = lane & 15, quad = lane >> 4;
  int n0 = blockIdx.x * 128, m0 = blockIdx.y * 128;
  int wm = (wave & 1) * 64, wn = (wave >> 1) * 64;
  f32x4 acc[4][4] = {};
  int sr = t >> 3, sc = (t & 7) * 8;   // staging: 8 thr/row, 8 elems each
  float wsc4[4];
  #pragma unroll
  for (int p = 0; p < 4; p++) wsc4[p] = wscale[n0 + p * 32 + sr];
  for (int k0 = 0; k0 < K; k0 += 64) {
    __syncthreads();
    #pragma unroll
    for (int p = 0; p < 4; p++) {
      int r = p * 32 + sr;
      *(int4*)&As[r][sc] = *(const int4*)&A[(size_t)(m0 + r) * K + k0 + sc];
      union { bf16x8 v; __bf16 h[8]; } q;
      if (bf) {
        union { int4 v; __bf16 h[8]; } u;
        u.v = *(const int4*)((const __bf16*)W + (size_t)(n0 + r) * K + k0 + sc);
        #pragma unroll
        for (int j = 0; j < 8; j++) q.h[j] = (__bf16)qclamp((float)u.h[j], wsc4[p]);
      } else {
        const float* wp = (const float*)W + (size_t)(n0 + r) * K + k0 + sc;
        float4 a = *(const float4*)wp, b = *(const float4*)(wp + 4);
        q.h[0] = (__bf16)qclamp(a.x, wsc4[p]); q.h[1] = (__bf16)qclamp(a.y, wsc4[p]);
        q.h[2] = (__bf16)qclamp(a.z, wsc4[p]); q.h[3] = (__bf16)qclamp(a.w, wsc4[p]);
        q.h[4] = (__bf16)qclamp(b.x, wsc4[p]); q.h[5] = (__bf16)qclamp(b.y, wsc4[p]);
        q.h[6] = (__bf16)qclamp(b.z, wsc4[p]); q.h[7] = (__bf16)qclamp(b.w, wsc4[p]);
      }
      *(bf16x8*)&Ws[r][sc] = q.v;
    }
    __syncthreads();
    #pragma unroll
    for (int kk = 0; kk < 64; kk += 32) {
      bf16x8 af[4], bfr[4];
      #pragma unroll
      for (int i = 0; i < 4; i++) {
        af[i]  = *(const bf16x8*)&As[wm + i * 16 + l15][kk + quad * 8];
        bfr[i] = *(const bf16x8*)&Ws[wn + i * 16 + l15][kk + quad * 8];
      }
      #pragma unroll
      for (int i = 0; i < 4; i++)
        #pragma unroll
        for (int j = 0; j < 4; j++)
          acc[i][j] = __builtin_amdgcn_mfma_f32_16x16x32_bf16(af[i], bfr[j], acc[i][j], 0, 0, 0);
    }
  }
  float asc = slot_scale(aslot);
  #pragma unroll
  for (int j = 0; j < 4; j++) {
    int gn = n0 + wn + j * 16 + l15;
    float wsb = wscale[gn] * asc;
    float bv = ldin(bias, gn, bf);
    #pragma unroll
    for (int i = 0; i < 4; i++)
      #pragma unroll
      for (int r = 0; r < 4; r++) {
        int gm = m0 + wm + i * 16 + quad * 4 + r;   // C/D: col=lane&15, row=quad*4+reg (m89)
        float val = acc[i][j][r] * wsb + bv;
        if (MODE == 0) {
          ((float*)outp)[(size_t)(gn >> 7) * (SEQ * DH) + (size_t)(off + gm) * DH + (gn & 127)] = val;
        } else {
          size_t idx = (size_t)(off + gm) * DM + gn;
          if (bf) ((__bf16*)outp)[idx] = (__bf16)val; else ((float*)outp)[idx] = val;
        }
      }
  }
}

// ===== Flash attention: Br=128 (4 waves x 32 rows), Bc=64, full softmax =====
__global__ __launch_bounds__(256, 2)
void flash_attn_k(const __bf16* __restrict__ Qb, const __bf16* __restrict__ Kb,
                  const __bf16* __restrict__ Vt, float* __restrict__ O) {
  __shared__ __bf16 Ks[64][136];
  __shared__ __bf16 Vs[128][72];   // [d][kc]  (V pre-transposed in global)
  __shared__ __bf16 Ps[128][72];   // [qr][kc] per-wave-private row ranges
  const int t = threadIdx.x, lane = t & 63, wave = t >> 6;
  const int l15 = lane & 15, quad = lane >> 4;
  const int h = blockIdx.y, s0 = blockIdx.x * 128, qr = wave * 32;
  const float fscale = 0.08838834764831845f * 1.4426950408889634f;  // sm_scale*log2e

  bf16x8 qf[2][4];
  #pragma unroll
  for (int mi = 0; mi < 2; mi++)
    #pragma unroll
    for (int kk = 0; kk < 4; kk++)
      qf[mi][kk] = *(const bf16x8*)&Qb[(size_t)(h * SEQ + s0 + qr + mi * 16 + l15) * DH + kk * 32 + quad * 8];

  f32x4 accO[2][8] = {};
  float m_st[2][4], l_st[2][4];
  #pragma unroll
  for (int mi = 0; mi < 2; mi++)
    #pragma unroll
    for (int r = 0; r < 4; r++) { m_st[mi][r] = -1e30f; l_st[mi][r] = 0.f; }

  for (int kt = 0; kt < SEQ / 64; kt++) {
    __syncthreads();
    #pragma unroll
    for (int p = 0; p < 4; p++) {
      int r = p * 16 + (t >> 4), c = (t & 15) * 8;
      *(int4*)&Ks[r][c] = *(const int4*)&Kb[(size_t)(h * SEQ + kt * 64 + r) * DH + c];
    }
    #pragma unroll
    for (int p = 0; p < 4; p++) {
      int r = p * 32 + (t >> 3), c = (t & 7) * 8;
      *(int4*)&Vs[r][c] = *(const int4*)&Vt[(size_t)(h * DH + r) * SEQ + kt * 64 + c];
    }
    __syncthreads();

    f32x4 accS[2][4] = {};
    #pragma unroll
    for (int kk = 0; kk < 4; kk++) {
      bf16x8 bk[4];
      #pragma unroll
      for (int ni = 0; ni < 4; ni++)
        bk[ni] = *(const bf16x8*)&Ks[ni * 16 + l15][kk * 32 + quad * 8];
      #pragma unroll
      for (int mi = 0; mi < 2; mi++)
        #pragma unroll
        for (int ni = 0; ni < 4; ni++)
          accS[mi][ni] = __builtin_amdgcn_mfma_f32_16x16x32_bf16(qf[mi][kk], bk[ni], accS[mi][ni], 0, 0, 0);
    }

    float al[2][4];
    #pragma unroll
    for (int mi = 0; mi < 2; mi++)
      #pragma unroll
      for (int r = 0; r < 4; r++) {
        float rm = fmaxf(fmaxf(accS[mi][0][r], accS[mi][1][r]), fmaxf(accS[mi][2][r], accS[mi][3][r]));
        #pragma unroll
        for (int off = 8; off > 0; off >>= 1) rm = fmaxf(rm, __shfl_xor(rm, off));
        float mn = fmaxf(m_st[mi][r], rm);
        al[mi][r] = exp2f((m_st[mi][r] - mn) * fscale);
        m_st[mi][r] = mn;
      }
    #pragma unroll
    for (int mi = 0; mi < 2; mi++)
      #pragma unroll
      for (int r = 0; r < 4; r++) {
        float rs = 0.f;
        #pragma unroll
        for (int ni = 0; ni < 4; ni++) {
          float pv = exp2f((accS[mi][ni][r] - m_st[mi][r]) * fscale);
          accS[mi][ni][r] = pv;
          rs += pv;
        }
        #pragma unroll
        for (int off = 8; off > 0; off >>= 1) rs += __shfl_xor(rs, off);
        l_st[mi][r] = l_st[mi][r] * al[mi][r] + rs;
      }
    #pragma unroll
    for (int mi = 0; mi < 2; mi++)
      #pragma unroll
      for (int di = 0; di < 8; di++)
        #pragma unroll
        for (int r = 0; r < 4; r++)
          accO[mi][di][r] *= al[mi][r];
    // P: C-layout regs -> LDS (A-layout source for PV), per-wave-private rows
    #pragma unroll
    for (int mi = 0; mi < 2; mi++)
      #pragma unroll
      for (int ni = 0; ni < 4; ni++)
        #pragma unroll
        for (int r = 0; r < 4; r++)
          Ps[qr + mi * 16 + quad * 4 + r][ni * 16 + l15] = (__bf16)accS[mi][ni][r];
    __syncthreads();
    #pragma unroll
    for (int kk2 = 0; kk2 < 2; kk2++) {
      bf16x8 pa[2], vb[8];
      #pragma unroll
      for (int mi = 0; mi < 2; mi++)
        pa[mi] = *(const bf16x8*)&Ps[qr + mi * 16 + l15][kk2 * 32 + quad * 8];
      #pragma unroll
      for (int di = 0; di < 8; di++)
        vb[di] = *(const bf16x8*)&Vs[di * 16 + l15][kk2 * 32 + quad * 8];
      #pragma unroll
      for (int mi = 0; mi < 2; mi++)
        #pragma unroll
        for (int di = 0; di < 8; di++)
          accO[mi][di] = __builtin_amdgcn_mfma_f32_16x16x32_bf16(pa[mi], vb[di], accO[mi][di], 0, 0, 0);
    }
  }
  #pragma unroll
  for (int mi = 0; mi < 2; mi++)
    #pragma unroll
    for (int r = 0; r < 4; r++) {
      float inv = 1.0f / l_st[mi][r];
      int gs = s0 + qr + mi * 16 + quad * 4 + r;
      #pragma unroll
      for (int di = 0; di < 8; di++)
        O[(size_t)gs * DM + h * DH + di * 16 + l15] = accO[mi][di][r] * inv;
    }
}

extern "C" void kernel_launch(void* const* d_in, const int* in_sizes, int n_in,
                              void* d_out, int out_size, void* d_ws, size_t ws_size,
                              hipStream_t stream) {
  (void)in_sizes; (void)n_in; (void)out_size; (void)ws_size;
  const void* hs   = d_in[0];
  const void* es   = d_in[1];
  const void* cosb = d_in[2];
  const void* sinb = d_in[3];
  const void* W[8]; const void* Bv[8];
  for (int i = 0; i < 8; i++) { W[i] = d_in[4 + 2 * i]; Bv[i] = d_in[5 + 2 * i]; }
  const void* nq  = d_in[20];
  const void* nk  = d_in[21];
  const void* naq = d_in[22];
  const void* nak = d_in[23];

  char* ws = (char*)d_ws;
  size_t off = 0;
  auto take = [&](size_t b) { char* p = ws + off; off += (b + 255) & ~(size_t)255; return p; };
  unsigned* slots = (unsigned*)take(64);                    // 9 scale slots + flag @ byte 48
  int* flagp = (int*)((char*)slots + 48);
  float*  wsc  = (float*)take(8ull * DM * 4);               // per-row weight scales
  // bufA: hq(8MB)+eq(1MB) during QKV phase; aliased by attnq (9.44MB) afterwards
  char*   bufA = take((size_t)SEQ * DM * 2);
  __bf16* hq    = (__bf16*)bufA;
  __bf16* eq    = (__bf16*)(bufA + (size_t)L_IMG * DM * 2);
  __bf16* attnq = (__bf16*)bufA;
  // bufB: qkvf fp32 during QKV phase; aliased by attnf afterwards
  float*  qkvf  = (float*)take((size_t)NH * SEQ * DH * 4);
  float*  attnf = qkvf;
  __bf16* qb  = (__bf16*)take((size_t)NH * SEQ * DH * 2);
  __bf16* kb  = (__bf16*)take((size_t)NH * SEQ * DH * 2);
  __bf16* vtb = (__bf16*)take((size_t)NH * SEQ * DH * 2);
  // total ws: ~57 MB

  hipMemsetAsync(slots, 0, 64, stream);
  detect_k<<<1, 64, 0, stream>>>(cosb, flagp);

  Ptrs8 win;
  for (int i = 0; i < 8; i++) win.p[i] = W[i];
  weight_scales_k<<<dim3(DM, 8), 256, 0, stream>>>(win, wsc, flagp);

  absmax_in_k<<<1024, 256, 0, stream>>>(hs, L_IMG * DM, slots + 0, flagp);
  absmax_in_k<<<256, 256, 0, stream>>>(es, L_TXT * DM, slots + 1, flagp);
  quant_int_in_k<<<L_IMG * DM / 256, 256, 0, stream>>>(hs, L_IMG * DM, slots + 0, hq, flagp);
  quant_int_in_k<<<L_TXT * DM / 256, 256, 0, stream>>>(es, L_TXT * DM, slots + 1, eq, flagp);

  for (int tns = 0; tns < 3; tns++) {
    gemm_bt<0><<<dim3(16, 16), 256, 0, stream>>>(hq, W[tns], wsc + tns * DM,
                                                 slots + 0, Bv[tns], qkvf, flagp, L_TXT);
    gemm_bt<0><<<dim3(16, 2), 256, 0, stream>>>(eq, W[3 + tns], wsc + (3 + tns) * DM,
                                                slots + 1, Bv[3 + tns], qkvf, flagp, 0);
    if (tns == 0) {
      rmsnorm_absmax_k<<<NH * SEQ / 4, 256, 0, stream>>>(qkvf, nq, naq, slots + 2, slots + 3, flagp);
      quant_rope_k<<<NH * SEQ * 64 / 256, 256, 0, stream>>>(qkvf, cosb, sinb, slots + 2, slots + 3, qb, flagp);
    } else if (tns == 1) {
      rmsnorm_absmax_k<<<NH * SEQ / 4, 256, 0, stream>>>(qkvf, nk, nak, slots + 4, slots + 5, flagp);
      quant_rope_k<<<NH * SEQ * 64 / 256, 256, 0, stream>>>(qkvf, cosb, sinb, slots + 4, slots + 5, kb, flagp);
    } else {
      absmax_v_k<<<1024, 256, 0, stream>>>(qkvf, slots + 6, slots + 7);
      quant_transpose_v_k<<<dim3(SEQ / 64, DH / 64, NH), 256, 0, stream>>>(qkvf, slots + 6, slots + 7, vtb);
    }
  }

  flash_attn_k<<<dim3(SEQ / 128, NH), 256, 0, stream>>>(qb, kb, vtb, attnf);

  absmax_f32_k<<<1024, 256, 0, stream>>>(attnf, SEQ * DM, slots + 8);
  quant_int_f32_k<<<SEQ * DM / 256, 256, 0, stream>>>(attnf, SEQ * DM, slots + 8, attnq);

  // outputs: img rows [0,2048) then enc rows [2048,2304) in flat [2304][2048]
  gemm_bt<1><<<dim3(16, 16), 256, 0, stream>>>(attnq + (size_t)L_TXT * DM, W[6],
                                               wsc + 6 * DM, slots + 8, Bv[6], d_out, flagp, 0);
  gemm_bt<1><<<dim3(16, 2), 256, 0, stream>>>(attnq, W[7], wsc + 7 * DM,
                                              slots + 8, Bv[7], d_out, flagp, L_IMG);
}

// Round 3
// 1652.255 us; speedup vs baseline: 1.4920x; 1.4920x over previous
//
#include <hip/hip_runtime.h>

// ===== Problem constants =====
constexpr int L_TXT = 256, L_IMG = 2048, SEQ = 2304;
constexpr int DM = 2048, NH = 16, DH = 128;

typedef __attribute__((ext_vector_type(8))) __bf16 bf16x8;
typedef __attribute__((ext_vector_type(4))) float f32x4;

// Runtime dtype flag: 0 = fp32 storage, 1 = bf16 storage. Detected from
// rope_cos[0][0]==1.0f (fp32 -> low u16 is 0x0000; bf16 -> 0x3F80).
__device__ __forceinline__ float ldin(const void* p, size_t i, int bf) {
  return bf ? (float)((const __bf16*)p)[i] : ((const float*)p)[i];
}

// slots: 0:h 1:e 2:q_txt 3:q_img 4:k_txt 5:k_img 6:v_txt 7:v_img 8:attn_out; int flag at byte 48
__device__ __forceinline__ float slot_scale(const unsigned* s) {
  return fmaxf(__uint_as_float(*s) / 127.0f, 1e-8f);
}
__device__ __forceinline__ float qclamp(float x, float sc) {
  float q = rintf(x / sc);                 // RNE, matches jnp.round
  return fminf(fmaxf(q, -127.0f), 127.0f);
}
__device__ __forceinline__ float block_allmax(float v) {
  #pragma unroll
  for (int off = 32; off > 0; off >>= 1) v = fmaxf(v, __shfl_xor(v, off));
  __shared__ float sm[4];
  __syncthreads();
  if ((threadIdx.x & 63) == 0) sm[threadIdx.x >> 6] = v;
  __syncthreads();
  return fmaxf(fmaxf(sm[0], sm[1]), fmaxf(sm[2], sm[3]));
}

__global__ void detect_k(const void* cosp, int* flag) {
  if (threadIdx.x == 0) *flag = (((const unsigned short*)cosp)[0] != 0) ? 1 : 0;
}

// ===== Per-row weight scales (quantization itself fused into GEMM staging) =====
struct Ptrs8 { const void* p[8]; };
__global__ void weight_scales_k(Ptrs8 win, float* __restrict__ scales, const int* __restrict__ flagp) {
  const int bf = *flagp;
  int row = blockIdx.x, mat = blockIdx.y, t = threadIdx.x;
  const void* w = win.p[mat];
  size_t base = (size_t)row * DM;
  float m = 0.f;
  for (int c = t; c < DM; c += 256) m = fmaxf(m, fabsf(ldin(w, base + c, bf)));
  m = block_allmax(m);
  if (t == 0) scales[mat * DM + row] = fmaxf(m / 127.0f, 1e-8f);
}

// ===== Global absmax reductions (256 blocks -> 256 atomics: contention-safe) =====
__global__ void absmax_in_k(const void* __restrict__ x, int n, unsigned* slot, const int* __restrict__ flagp) {
  const int bf = *flagp;
  int i = blockIdx.x * 256 + threadIdx.x, stride = gridDim.x * 256;
  float m = 0.f;
  for (; i < n; i += stride) m = fmaxf(m, fabsf(ldin(x, i, bf)));
  m = block_allmax(m);
  if (threadIdx.x == 0) atomicMax(slot, __float_as_uint(m));
}
__global__ void absmax_f32_k(const float* __restrict__ x, int n, unsigned* slot) {
  int i = blockIdx.x * 256 + threadIdx.x, stride = gridDim.x * 256;
  float m = 0.f;
  for (; i < n; i += stride) m = fmaxf(m, fabsf(x[i]));
  m = block_allmax(m);
  if (threadIdx.x == 0) atomicMax(slot, __float_as_uint(m));
}
// v tensor [NH][SEQ][DH]: txt rows (s<256) and img rows have separate scales
__global__ void absmax_v_k(const float* __restrict__ x, unsigned* st, unsigned* si) {
  int i = blockIdx.x * 256 + threadIdx.x, stride = gridDim.x * 256;
  const int n = NH * SEQ * DH;
  float mt = 0.f, mg = 0.f;
  for (; i < n; i += stride) {
    float a = fabsf(x[i]);
    int s = (i >> 7) % SEQ;
    if (s < L_TXT) mt = fmaxf(mt, a); else mg = fmaxf(mg, a);
  }
  mt = block_allmax(mt);
  __syncthreads();
  mg = block_allmax(mg);
  if (threadIdx.x == 0) { atomicMax(st, __float_as_uint(mt)); atomicMax(si, __float_as_uint(mg)); }
}

// ===== Quantize to INT-grid bf16 (scale applied in GEMM epilogue) =====
__global__ void quant_int_in_k(const void* __restrict__ x, int n, const unsigned* __restrict__ slot,
                               __bf16* __restrict__ out, const int* __restrict__ flagp) {
  const int bf = *flagp;
  int i = blockIdx.x * 256 + threadIdx.x;
  if (i >= n) return;
  float sc = slot_scale(slot);
  out[i] = (__bf16)qclamp(ldin(x, i, bf), sc);
}
__global__ void quant_int_f32_k(const float* __restrict__ x, int n,
                                const unsigned* __restrict__ slot, __bf16* __restrict__ out) {
  int i = blockIdx.x * 256 + threadIdx.x;
  if (i >= n) return;
  float sc = slot_scale(slot);
  out[i] = (__bf16)qclamp(x[i], sc);
}

// ===== RMSNorm in-place on [NH][SEQ][DH] fp32 + per-range absmax =====
// ATOMIC-CONTENTION FIX (round 2 -> 3): old version did one atomicMax per wave
// (36,864 atomics on one cacheline -> 423 us serialization, measured). Now:
// 256 blocks x 16 waves, grid-stride 9 rows/wave, per-lane running maxima,
// one block-level reduce, 2 atomics per block (512 total).
__global__ void rmsnorm_absmax_k(float* __restrict__ x, const void* __restrict__ w_img,
                                 const void* __restrict__ w_txt,
                                 unsigned* slot_txt, unsigned* slot_img, const int* __restrict__ flagp) {
  const int bf = *flagp;
  const int t = threadIdx.x, lane = t & 63, wave = t >> 6;     // 16 waves/block
  const int nwaves = 256 * 16;
  float wt = ldin(w_txt, lane, bf), wt1 = ldin(w_txt, lane + 64, bf);
  float wi = ldin(w_img, lane, bf), wi1 = ldin(w_img, lane + 64, bf);
  float mt = 0.f, mg = 0.f;
  for (int row = blockIdx.x * 16 + wave; row < NH * SEQ; row += nwaves) {
    int s = row % SEQ;
    float* p = x + (size_t)row * DH;
    float v0 = p[lane], v1 = p[lane + 64];
    float ss = v0 * v0 + v1 * v1;
    #pragma unroll
    for (int off = 32; off > 0; off >>= 1) ss += __shfl_xor(ss, off);
    float r = rsqrtf(ss * (1.0f / 128.0f) + 1e-6f);
    bool txt = (s < L_TXT);
    float y0 = v0 * r * (txt ? wt : wi);
    float y1 = v1 * r * (txt ? wt1 : wi1);
    p[lane] = y0; p[lane + 64] = y1;
    float am = fmaxf(fabsf(y0), fabsf(y1));
    if (txt) mt = fmaxf(mt, am); else mg = fmaxf(mg, am);
  }
  #pragma unroll
  for (int off = 32; off > 0; off >>= 1) {
    mt = fmaxf(mt, __shfl_xor(mt, off));
    mg = fmaxf(mg, __shfl_xor(mg, off));
  }
  __shared__ float smt[16], smg[16];
  if (lane == 0) { smt[wave] = mt; smg[wave] = mg; }
  __syncthreads();
  if (t == 0) {
    float a = 0.f, b = 0.f;
    #pragma unroll
    for (int i = 0; i < 16; i++) { a = fmaxf(a, smt[i]); b = fmaxf(b, smg[i]); }
    atomicMax(slot_txt, __float_as_uint(a));
    atomicMax(slot_img, __float_as_uint(b));
  }
}

// ===== quantize (dequantized value) + RoPE + cast bf16, per pair =====
__global__ void quant_rope_k(const float* __restrict__ x, const void* __restrict__ cosb,
                             const void* __restrict__ sinb, const unsigned* slot_txt,
                             const unsigned* slot_img, __bf16* __restrict__ out,
                             const int* __restrict__ flagp) {
  const int bf = *flagp;
  int i = blockIdx.x * 256 + threadIdx.x;  // pair index over NH*SEQ*64
  int pr = i & 63;
  int s = (i >> 6) % SEQ;
  size_t base = (size_t)(i >> 6) * DH + pr * 2;
  float sc = slot_scale(s < L_TXT ? slot_txt : slot_img);
  float x0 = x[base], x1 = x[base + 1];
  float q0 = qclamp(x0, sc) * sc;
  float q1 = qclamp(x1, sc) * sc;
  float c0 = ldin(cosb, s * DH + 2 * pr, bf), c1 = ldin(cosb, s * DH + 2 * pr + 1, bf);
  float s0 = ldin(sinb, s * DH + 2 * pr, bf), s1 = ldin(sinb, s * DH + 2 * pr + 1, bf);
  out[base]     = (__bf16)(q0 * c0 - q1 * s0);
  out[base + 1] = (__bf16)(q1 * c1 + q0 * s1);
}

// ===== V: quantize (dequantized) + transpose [NH][SEQ][DH] -> [NH][DH][SEQ] =====
__global__ void quant_transpose_v_k(const float* __restrict__ v, const unsigned* st,
                                    const unsigned* si, __bf16* __restrict__ vt) {
  __shared__ float tile[64][65];
  int t = threadIdx.x;
  int s0 = blockIdx.x * 64, d0 = blockIdx.y * 64, h = blockIdx.z;
  #pragma unroll
  for (int i = 0; i < 16; i++) {
    int r = i * 4 + (t >> 6), c = t & 63;
    tile[r][c] = v[((size_t)(h * SEQ) + s0 + r) * DH + d0 + c];
  }
  __syncthreads();
  float sc = slot_scale(s0 < L_TXT ? st : si);
  #pragma unroll
  for (int i = 0; i < 16; i++) {
    int d = i * 4 + (t >> 6), s = t & 63;
    float q = qclamp(tile[s][d], sc) * sc;
    vt[((size_t)(h * DH) + d0 + d) * SEQ + s0 + s] = (__bf16)q;
  }
}

// ===== GEMM: C[m,n] = ascale*wscale[n]*(Aq @ Wq^T) + bias[n] =====
// A: Mx2048 int-bf16 (internal). W: raw input (fp32 or bf16), quantized on the
// fly during LDS staging using per-row scales. 128x128 tile, BK=64, 4 waves.
// MODE 0: fp32 head-split out [(n>>7)][off+m][n&127]; MODE 1: out rows at (m+off)*2048+n, dtype per flag
template<int MODE>
__global__ __launch_bounds__(256, 2)
void gemm_bt(const __bf16* __restrict__ A, const void* __restrict__ W,
             const float* __restrict__ wscale, const unsigned* __restrict__ aslot,
             const void* __restrict__ bias, void* __restrict__ outp,
             const int* __restrict__ flagp, int off) {
  const int bf = *flagp;
  constexpr int K = 2048;
  __shared__ __bf16 As[128][72];   // +8 pad
  __shared__ __bf16 Ws[128][72];
  int t = threadIdx.x, lane = t & 63, wave = t >> 6;
  int l15 = lane & 15, quad = lane >> 4;
  int n0 = blockIdx.x * 128, m0 = blockIdx.y * 128;
  int wm = (wave & 1) * 64, wn = (wave >> 1) * 64;
  f32x4 acc[4][4] = {};
  int sr = t >> 3, sc = (t & 7) * 8;   // staging: 8 thr/row, 8 elems each
  float wsc4[4];
  #pragma unroll
  for (int p = 0; p < 4; p++) wsc4[p] = wscale[n0 + p * 32 + sr];
  for (int k0 = 0; k0 < K; k0 += 64) {
    __syncthreads();
    #pragma unroll
    for (int p = 0; p < 4; p++) {
      int r = p * 32 + sr;
      *(int4*)&As[r][sc] = *(const int4*)&A[(size_t)(m0 + r) * K + k0 + sc];
      union { bf16x8 v; __bf16 h[8]; } q;
      if (bf) {
        union { int4 v; __bf16 h[8]; } u;
        u.v = *(const int4*)((const __bf16*)W + (size_t)(n0 + r) * K + k0 + sc);
        #pragma unroll
        for (int j = 0; j < 8; j++) q.h[j] = (__bf16)qclamp((float)u.h[j], wsc4[p]);
      } else {
        const float* wp = (const float*)W + (size_t)(n0 + r) * K + k0 + sc;
        float4 a = *(const float4*)wp, b = *(const float4*)(wp + 4);
        q.h[0] = (__bf16)qclamp(a.x, wsc4[p]); q.h[1] = (__bf16)qclamp(a.y, wsc4[p]);
        q.h[2] = (__bf16)qclamp(a.z, wsc4[p]); q.h[3] = (__bf16)qclamp(a.w, wsc4[p]);
        q.h[4] = (__bf16)qclamp(b.x, wsc4[p]); q.h[5] = (__bf16)qclamp(b.y, wsc4[p]);
        q.h[6] = (__bf16)qclamp(b.z, wsc4[p]); q.h[7] = (__bf16)qclamp(b.w, wsc4[p]);
      }
      *(bf16x8*)&Ws[r][sc] = q.v;
    }
    __syncthreads();
    #pragma unroll
    for (int kk = 0; kk < 64; kk += 32) {
      bf16x8 af[4], bfr[4];
      #pragma unroll
      for (int i = 0; i < 4; i++) {
        af[i]  = *(const bf16x8*)&As[wm + i * 16 + l15][kk + quad * 8];
        bfr[i] = *(const bf16x8*)&Ws[wn + i * 16 + l15][kk + quad * 8];
      }
      #pragma unroll
      for (int i = 0; i < 4; i++)
        #pragma unroll
        for (int j = 0; j < 4; j++)
          acc[i][j] = __builtin_amdgcn_mfma_f32_16x16x32_bf16(af[i], bfr[j], acc[i][j], 0, 0, 0);
    }
  }
  float asc = slot_scale(aslot);
  #pragma unroll
  for (int j = 0; j < 4; j++) {
    int gn = n0 + wn + j * 16 + l15;
    float wsb = wscale[gn] * asc;
    float bv = ldin(bias, gn, bf);
    #pragma unroll
    for (int i = 0; i < 4; i++)
      #pragma unroll
      for (int r = 0; r < 4; r++) {
        int gm = m0 + wm + i * 16 + quad * 4 + r;   // C/D: col=lane&15, row=quad*4+reg (m89)
        float val = acc[i][j][r] * wsb + bv;
        if (MODE == 0) {
          ((float*)outp)[(size_t)(gn >> 7) * (SEQ * DH) + (size_t)(off + gm) * DH + (gn & 127)] = val;
        } else {
          size_t idx = (size_t)(off + gm) * DM + gn;
          if (bf) ((__bf16*)outp)[idx] = (__bf16)val; else ((float*)outp)[idx] = val;
        }
      }
  }
}

// ===== Flash attention: Br=128 (4 waves x 32 rows), Bc=64, full softmax =====
__global__ __launch_bounds__(256, 2)
void flash_attn_k(const __bf16* __restrict__ Qb, const __bf16* __restrict__ Kb,
                  const __bf16* __restrict__ Vt, float* __restrict__ O) {
  __shared__ __bf16 Ks[64][136];
  __shared__ __bf16 Vs[128][72];   // [d][kc]  (V pre-transposed in global)
  __shared__ __bf16 Ps[128][72];   // [qr][kc] per-wave-private row ranges
  const int t = threadIdx.x, lane = t & 63, wave = t >> 6;
  const int l15 = lane & 15, quad = lane >> 4;
  const int h = blockIdx.y, s0 = blockIdx.x * 128, qr = wave * 32;
  const float fscale = 0.08838834764831845f * 1.4426950408889634f;  // sm_scale*log2e

  bf16x8 qf[2][4];
  #pragma unroll
  for (int mi = 0; mi < 2; mi++)
    #pragma unroll
    for (int kk = 0; kk < 4; kk++)
      qf[mi][kk] = *(const bf16x8*)&Qb[(size_t)(h * SEQ + s0 + qr + mi * 16 + l15) * DH + kk * 32 + quad * 8];

  f32x4 accO[2][8] = {};
  float m_st[2][4], l_st[2][4];
  #pragma unroll
  for (int mi = 0; mi < 2; mi++)
    #pragma unroll
    for (int r = 0; r < 4; r++) { m_st[mi][r] = -1e30f; l_st[mi][r] = 0.f; }

  for (int kt = 0; kt < SEQ / 64; kt++) {
    __syncthreads();
    #pragma unroll
    for (int p = 0; p < 4; p++) {
      int r = p * 16 + (t >> 4), c = (t & 15) * 8;
      *(int4*)&Ks[r][c] = *(const int4*)&Kb[(size_t)(h * SEQ + kt * 64 + r) * DH + c];
    }
    #pragma unroll
    for (int p = 0; p < 4; p++) {
      int r = p * 32 + (t >> 3), c = (t & 7) * 8;
      *(int4*)&Vs[r][c] = *(const int4*)&Vt[(size_t)(h * DH + r) * SEQ + kt * 64 + c];
    }
    __syncthreads();

    f32x4 accS[2][4] = {};
    #pragma unroll
    for (int kk = 0; kk < 4; kk++) {
      bf16x8 bk[4];
      #pragma unroll
      for (int ni = 0; ni < 4; ni++)
        bk[ni] = *(const bf16x8*)&Ks[ni * 16 + l15][kk * 32 + quad * 8];
      #pragma unroll
      for (int mi = 0; mi < 2; mi++)
        #pragma unroll
        for (int ni = 0; ni < 4; ni++)
          accS[mi][ni] = __builtin_amdgcn_mfma_f32_16x16x32_bf16(qf[mi][kk], bk[ni], accS[mi][ni], 0, 0, 0);
    }

    float al[2][4];
    #pragma unroll
    for (int mi = 0; mi < 2; mi++)
      #pragma unroll
      for (int r = 0; r < 4; r++) {
        float rm = fmaxf(fmaxf(accS[mi][0][r], accS[mi][1][r]), fmaxf(accS[mi][2][r], accS[mi][3][r]));
        #pragma unroll
        for (int off = 8; off > 0; off >>= 1) rm = fmaxf(rm, __shfl_xor(rm, off));
        float mn = fmaxf(m_st[mi][r], rm);
        al[mi][r] = exp2f((m_st[mi][r] - mn) * fscale);
        m_st[mi][r] = mn;
      }
    #pragma unroll
    for (int mi = 0; mi < 2; mi++)
      #pragma unroll
      for (int r = 0; r < 4; r++) {
        float rs = 0.f;
        #pragma unroll
        for (int ni = 0; ni < 4; ni++) {
          float pv = exp2f((accS[mi][ni][r] - m_st[mi][r]) * fscale);
          accS[mi][ni][r] = pv;
          rs += pv;
        }
        #pragma unroll
        for (int off = 8; off > 0; off >>= 1) rs += __shfl_xor(rs, off);
        l_st[mi][r] = l_st[mi][r] * al[mi][r] + rs;
      }
    #pragma unroll
    for (int mi = 0; mi < 2; mi++)
      #pragma unroll
      for (int di = 0; di < 8; di++)
        #pragma unroll
        for (int r = 0; r < 4; r++)
          accO[mi][di][r] *= al[mi][r];
    // P: C-layout regs -> LDS (A-layout source for PV), per-wave-private rows
    #pragma unroll
    for (int mi = 0; mi < 2; mi++)
      #pragma unroll
      for (int ni = 0; ni < 4; ni++)
        #pragma unroll
        for (int r = 0; r < 4; r++)
          Ps[qr + mi * 16 + quad * 4 + r][ni * 16 + l15] = (__bf16)accS[mi][ni][r];
    __syncthreads();
    #pragma unroll
    for (int kk2 = 0; kk2 < 2; kk2++) {
      bf16x8 pa[2], vb[8];
      #pragma unroll
      for (int mi = 0; mi < 2; mi++)
        pa[mi] = *(const bf16x8*)&Ps[qr + mi * 16 + l15][kk2 * 32 + quad * 8];
      #pragma unroll
      for (int di = 0; di < 8; di++)
        vb[di] = *(const bf16x8*)&Vs[di * 16 + l15][kk2 * 32 + quad * 8];
      #pragma unroll
      for (int mi = 0; mi < 2; mi++)
        #pragma unroll
        for (int di = 0; di < 8; di++)
          accO[mi][di] = __builtin_amdgcn_mfma_f32_16x16x32_bf16(pa[mi], vb[di], accO[mi][di], 0, 0, 0);
    }
  }
  #pragma unroll
  for (int mi = 0; mi < 2; mi++)
    #pragma unroll
    for (int r = 0; r < 4; r++) {
      float inv = 1.0f / l_st[mi][r];
      int gs = s0 + qr + mi * 16 + quad * 4 + r;
      #pragma unroll
      for (int di = 0; di < 8; di++)
        O[(size_t)gs * DM + h * DH + di * 16 + l15] = accO[mi][di][r] * inv;
    }
}

extern "C" void kernel_launch(void* const* d_in, const int* in_sizes, int n_in,
                              void* d_out, int out_size, void* d_ws, size_t ws_size,
                              hipStream_t stream) {
  (void)in_sizes; (void)n_in; (void)out_size; (void)ws_size;
  const void* hs   = d_in[0];
  const void* es   = d_in[1];
  const void* cosb = d_in[2];
  const void* sinb = d_in[3];
  const void* W[8]; const void* Bv[8];
  for (int i = 0; i < 8; i++) { W[i] = d_in[4 + 2 * i]; Bv[i] = d_in[5 + 2 * i]; }
  const void* nq  = d_in[20];
  const void* nk  = d_in[21];
  const void* naq = d_in[22];
  const void* nak = d_in[23];

  char* ws = (char*)d_ws;
  size_t off = 0;
  auto take = [&](size_t b) { char* p = ws + off; off += (b + 255) & ~(size_t)255; return p; };
  unsigned* slots = (unsigned*)take(64);                    // 9 scale slots + flag @ byte 48
  int* flagp = (int*)((char*)slots + 48);
  float*  wsc  = (float*)take(8ull * DM * 4);               // per-row weight scales
  // bufA: hq(8MB)+eq(1MB) during QKV phase; aliased by attnq (9.44MB) afterwards
  char*   bufA = take((size_t)SEQ * DM * 2);
  __bf16* hq    = (__bf16*)bufA;
  __bf16* eq    = (__bf16*)(bufA + (size_t)L_IMG * DM * 2);
  __bf16* attnq = (__bf16*)bufA;
  // bufB: qkvf fp32 during QKV phase; aliased by attnf afterwards
  float*  qkvf  = (float*)take((size_t)NH * SEQ * DH * 4);
  float*  attnf = qkvf;
  __bf16* qb  = (__bf16*)take((size_t)NH * SEQ * DH * 2);
  __bf16* kb  = (__bf16*)take((size_t)NH * SEQ * DH * 2);
  __bf16* vtb = (__bf16*)take((size_t)NH * SEQ * DH * 2);
  // total ws: ~57 MB

  hipMemsetAsync(slots, 0, 64, stream);
  detect_k<<<1, 64, 0, stream>>>(cosb, flagp);

  Ptrs8 win;
  for (int i = 0; i < 8; i++) win.p[i] = W[i];
  weight_scales_k<<<dim3(DM, 8), 256, 0, stream>>>(win, wsc, flagp);

  absmax_in_k<<<256, 256, 0, stream>>>(hs, L_IMG * DM, slots + 0, flagp);
  absmax_in_k<<<256, 256, 0, stream>>>(es, L_TXT * DM, slots + 1, flagp);
  quant_int_in_k<<<L_IMG * DM / 256, 256, 0, stream>>>(hs, L_IMG * DM, slots + 0, hq, flagp);
  quant_int_in_k<<<L_TXT * DM / 256, 256, 0, stream>>>(es, L_TXT * DM, slots + 1, eq, flagp);

  for (int tns = 0; tns < 3; tns++) {
    gemm_bt<0><<<dim3(16, 16), 256, 0, stream>>>(hq, W[tns], wsc + tns * DM,
                                                 slots + 0, Bv[tns], qkvf, flagp, L_TXT);
    gemm_bt<0><<<dim3(16, 2), 256, 0, stream>>>(eq, W[3 + tns], wsc + (3 + tns) * DM,
                                                slots + 1, Bv[3 + tns], qkvf, flagp, 0);
    if (tns == 0) {
      rmsnorm_absmax_k<<<256, 1024, 0, stream>>>(qkvf, nq, naq, slots + 2, slots + 3, flagp);
      quant_rope_k<<<NH * SEQ * 64 / 256, 256, 0, stream>>>(qkvf, cosb, sinb, slots + 2, slots + 3, qb, flagp);
    } else if (tns == 1) {
      rmsnorm_absmax_k<<<256, 1024, 0, stream>>>(qkvf, nk, nak, slots + 4, slots + 5, flagp);
      quant_rope_k<<<NH * SEQ * 64 / 256, 256, 0, stream>>>(qkvf, cosb, sinb, slots + 4, slots + 5, kb, flagp);
    } else {
      absmax_v_k<<<256, 256, 0, stream>>>(qkvf, slots + 6, slots + 7);
      quant_transpose_v_k<<<dim3(SEQ / 64, DH / 64, NH), 256, 0, stream>>>(qkvf, slots + 6, slots + 7, vtb);
    }
  }

  flash_attn_k<<<dim3(SEQ / 128, NH), 256, 0, stream>>>(qb, kb, vtb, attnf);

  absmax_f32_k<<<256, 256, 0, stream>>>(attnf, SEQ * DM, slots + 8);
  quant_int_f32_k<<<SEQ * DM / 256, 256, 0, stream>>>(attnf, SEQ * DM, slots + 8, attnq);

  // outputs: img rows [0,2048) then enc rows [2048,2304) in flat [2304][2048]
  gemm_bt<1><<<dim3(16, 16), 256, 0, stream>>>(attnq + (size_t)L_TXT * DM, W[6],
                                               wsc + 6 * DM, slots + 8, Bv[6], d_out, flagp, 0);
  gemm_bt<1><<<dim3(16, 2), 256, 0, stream>>>(attnq, W[7], wsc + 7 * DM,
                                              slots + 8, Bv[7], d_out, flagp, L_IMG);
}

// Round 4
// 959.848 us; speedup vs baseline: 2.5683x; 1.7214x over previous
//
#include <hip/hip_runtime.h>

// ===== Problem constants =====
constexpr int L_TXT = 256, L_IMG = 2048, SEQ = 2304;
constexpr int DM = 2048, NH = 16, DH = 128;
constexpr int NSPLIT = 4;                  // flash split-K factor (36 tiles / 4 = 9)

typedef __attribute__((ext_vector_type(8))) __bf16 bf16x8;
typedef __attribute__((ext_vector_type(4))) float f32x4;

// Runtime dtype flag: 0 = fp32 storage, 1 = bf16 storage (detected from rope_cos[0]).
__device__ __forceinline__ float ldin(const void* p, size_t i, int bf) {
  return bf ? (float)((const __bf16*)p)[i] : ((const float*)p)[i];
}

// slots: 0:h 1:e 2:q_txt 3:q_img 4:k_txt 5:k_img 6:v_txt 7:v_img 8:attn_out; int flag at byte 48
__device__ __forceinline__ float slot_scale(const unsigned* s) {
  return fmaxf(__uint_as_float(*s) / 127.0f, 1e-8f);
}
__device__ __forceinline__ float qclamp(float x, float sc) {
  float q = rintf(x / sc);                 // RNE, matches jnp.round
  return fminf(fmaxf(q, -127.0f), 127.0f);
}
__device__ __forceinline__ float block_allmax(float v) {
  #pragma unroll
  for (int off = 32; off > 0; off >>= 1) v = fmaxf(v, __shfl_xor(v, off));
  __shared__ float sm[4];
  __syncthreads();
  if ((threadIdx.x & 63) == 0) sm[threadIdx.x >> 6] = v;
  __syncthreads();
  return fmaxf(fmaxf(sm[0], sm[1]), fmaxf(sm[2], sm[3]));
}

__global__ void detect_k(const void* cosp, int* flag) {
  if (threadIdx.x == 0) *flag = (((const unsigned short*)cosp)[0] != 0) ? 1 : 0;
}

struct Ptrs8 { const void* p[8]; };

// Scales only (fallback path: quantization fused in GEMM staging)
__global__ void weight_scales_k(Ptrs8 win, float* __restrict__ scales, const int* __restrict__ flagp) {
  const int bf = *flagp;
  int row = blockIdx.x, mat = blockIdx.y, t = threadIdx.x;
  const void* w = win.p[mat];
  size_t base = (size_t)row * DM;
  float m = 0.f;
  for (int c = t; c < DM; c += 256) m = fmaxf(m, fabsf(ldin(w, base + c, bf)));
  m = block_allmax(m);
  if (t == 0) scales[mat * DM + row] = fmaxf(m / 127.0f, 1e-8f);
}
// Scales + materialized int-grid bf16 weights (preferred: removes per-GEMM quant VALU + halves W fetch)
__global__ void quant_weights_k(Ptrs8 win, __bf16* __restrict__ wq, float* __restrict__ scales,
                                const int* __restrict__ flagp) {
  const int bf = *flagp;
  int row = blockIdx.x, mat = blockIdx.y, t = threadIdx.x;
  const void* w = win.p[mat];
  size_t base = (size_t)row * DM;
  float m = 0.f;
  for (int c = t; c < DM; c += 256) m = fmaxf(m, fabsf(ldin(w, base + c, bf)));
  m = block_allmax(m);
  float sc = fmaxf(m / 127.0f, 1e-8f);
  if (t == 0) scales[mat * DM + row] = sc;
  __bf16* q = wq + (size_t)mat * DM * DM + base;
  for (int c = t; c < DM; c += 256) q[c] = (__bf16)qclamp(ldin(w, base + c, bf), sc);
}

// ===== Global absmax reductions (256 blocks -> low atomic contention) =====
__global__ void absmax_in_k(const void* __restrict__ x, int n, unsigned* slot, const int* __restrict__ flagp) {
  const int bf = *flagp;
  int i = blockIdx.x * 256 + threadIdx.x, stride = gridDim.x * 256;
  float m = 0.f;
  for (; i < n; i += stride) m = fmaxf(m, fabsf(ldin(x, i, bf)));
  m = block_allmax(m);
  if (threadIdx.x == 0) atomicMax(slot, __float_as_uint(m));
}
__global__ void absmax_f32_k(const float* __restrict__ x, int n, unsigned* slot) {
  int i = blockIdx.x * 256 + threadIdx.x, stride = gridDim.x * 256;
  float m = 0.f;
  for (; i < n; i += stride) m = fmaxf(m, fabsf(x[i]));
  m = block_allmax(m);
  if (threadIdx.x == 0) atomicMax(slot, __float_as_uint(m));
}
__global__ void absmax_v_k(const float* __restrict__ x, unsigned* st, unsigned* si) {
  int i = blockIdx.x * 256 + threadIdx.x, stride = gridDim.x * 256;
  const int n = NH * SEQ * DH;
  float mt = 0.f, mg = 0.f;
  for (; i < n; i += stride) {
    float a = fabsf(x[i]);
    int s = (i >> 7) % SEQ;
    if (s < L_TXT) mt = fmaxf(mt, a); else mg = fmaxf(mg, a);
  }
  mt = block_allmax(mt);
  __syncthreads();
  mg = block_allmax(mg);
  if (threadIdx.x == 0) { atomicMax(st, __float_as_uint(mt)); atomicMax(si, __float_as_uint(mg)); }
}

// ===== Quantize to INT-grid bf16 =====
__global__ void quant_int_in_k(const void* __restrict__ x, int n, const unsigned* __restrict__ slot,
                               __bf16* __restrict__ out, const int* __restrict__ flagp) {
  const int bf = *flagp;
  int i = blockIdx.x * 256 + threadIdx.x;
  if (i >= n) return;
  float sc = slot_scale(slot);
  out[i] = (__bf16)qclamp(ldin(x, i, bf), sc);
}
__global__ void quant_int_f32_k(const float* __restrict__ x, int n,
                                const unsigned* __restrict__ slot, __bf16* __restrict__ out) {
  int i = blockIdx.x * 256 + threadIdx.x;
  if (i >= n) return;
  float sc = slot_scale(slot);
  out[i] = (__bf16)qclamp(x[i], sc);
}

// ===== RMSNorm in-place + per-range absmax (2 atomics/block; see round-3 fix) =====
__global__ void rmsnorm_absmax_k(float* __restrict__ x, const void* __restrict__ w_img,
                                 const void* __restrict__ w_txt,
                                 unsigned* slot_txt, unsigned* slot_img, const int* __restrict__ flagp) {
  const int bf = *flagp;
  const int t = threadIdx.x, lane = t & 63, wave = t >> 6;     // 16 waves/block
  const int nwaves = 256 * 16;
  float wt = ldin(w_txt, lane, bf), wt1 = ldin(w_txt, lane + 64, bf);
  float wi = ldin(w_img, lane, bf), wi1 = ldin(w_img, lane + 64, bf);
  float mt = 0.f, mg = 0.f;
  for (int row = blockIdx.x * 16 + wave; row < NH * SEQ; row += nwaves) {
    int s = row % SEQ;
    float* p = x + (size_t)row * DH;
    float v0 = p[lane], v1 = p[lane + 64];
    float ss = v0 * v0 + v1 * v1;
    #pragma unroll
    for (int off = 32; off > 0; off >>= 1) ss += __shfl_xor(ss, off);
    float r = rsqrtf(ss * (1.0f / 128.0f) + 1e-6f);
    bool txt = (s < L_TXT);
    float y0 = v0 * r * (txt ? wt : wi);
    float y1 = v1 * r * (txt ? wt1 : wi1);
    p[lane] = y0; p[lane + 64] = y1;
    float am = fmaxf(fabsf(y0), fabsf(y1));
    if (txt) mt = fmaxf(mt, am); else mg = fmaxf(mg, am);
  }
  #pragma unroll
  for (int off = 32; off > 0; off >>= 1) {
    mt = fmaxf(mt, __shfl_xor(mt, off));
    mg = fmaxf(mg, __shfl_xor(mg, off));
  }
  __shared__ float smt[16], smg[16];
  if (lane == 0) { smt[wave] = mt; smg[wave] = mg; }
  __syncthreads();
  if (t == 0) {
    float a = 0.f, b = 0.f;
    #pragma unroll
    for (int i = 0; i < 16; i++) { a = fmaxf(a, smt[i]); b = fmaxf(b, smg[i]); }
    atomicMax(slot_txt, __float_as_uint(a));
    atomicMax(slot_img, __float_as_uint(b));
  }
}

// ===== quantize + RoPE + cast bf16 =====
__global__ void quant_rope_k(const float* __restrict__ x, const void* __restrict__ cosb,
                             const void* __restrict__ sinb, const unsigned* slot_txt,
                             const unsigned* slot_img, __bf16* __restrict__ out,
                             const int* __restrict__ flagp) {
  const int bf = *flagp;
  int i = blockIdx.x * 256 + threadIdx.x;
  int pr = i & 63;
  int s = (i >> 6) % SEQ;
  size_t base = (size_t)(i >> 6) * DH + pr * 2;
  float sc = slot_scale(s < L_TXT ? slot_txt : slot_img);
  float x0 = x[base], x1 = x[base + 1];
  float q0 = qclamp(x0, sc) * sc;
  float q1 = qclamp(x1, sc) * sc;
  float c0 = ldin(cosb, s * DH + 2 * pr, bf), c1 = ldin(cosb, s * DH + 2 * pr + 1, bf);
  float s0 = ldin(sinb, s * DH + 2 * pr, bf), s1 = ldin(sinb, s * DH + 2 * pr + 1, bf);
  out[base]     = (__bf16)(q0 * c0 - q1 * s0);
  out[base + 1] = (__bf16)(q1 * c1 + q0 * s1);
}

// ===== V: quantize + transpose [NH][SEQ][DH] -> [NH][DH][SEQ] =====
__global__ void quant_transpose_v_k(const float* __restrict__ v, const unsigned* st,
                                    const unsigned* si, __bf16* __restrict__ vt) {
  __shared__ float tile[64][65];
  int t = threadIdx.x;
  int s0 = blockIdx.x * 64, d0 = blockIdx.y * 64, h = blockIdx.z;
  #pragma unroll
  for (int i = 0; i < 16; i++) {
    int r = i * 4 + (t >> 6), c = t & 63;
    tile[r][c] = v[((size_t)(h * SEQ) + s0 + r) * DH + d0 + c];
  }
  __syncthreads();
  float sc = slot_scale(s0 < L_TXT ? st : si);
  #pragma unroll
  for (int i = 0; i < 16; i++) {
    int d = i * 4 + (t >> 6), s = t & 63;
    float q = qclamp(tile[s][d], sc) * sc;
    vt[((size_t)(h * DH) + d0 + d) * SEQ + s0 + s] = (__bf16)q;
  }
}

// ===== GEMM: C[m,n] = ascale*wscale[n]*(Aq @ Wq^T) + bias[n] =====
// QW=1: W pre-quantized int-grid bf16 (straight int4 staging). QW=0: quantize on the fly.
template<int MODE, int QW>
__global__ __launch_bounds__(256, 2)
void gemm_bt(const __bf16* __restrict__ A, const void* __restrict__ W,
             const float* __restrict__ wscale, const unsigned* __restrict__ aslot,
             const void* __restrict__ bias, void* __restrict__ outp,
             const int* __restrict__ flagp, int off) {
  const int bf = *flagp;
  constexpr int K = 2048;
  __shared__ __bf16 As[128][72];
  __shared__ __bf16 Ws[128][72];
  int t = threadIdx.x, lane = t & 63, wave = t >> 6;
  int l15 = lane & 15, quad = lane >> 4;
  int n0 = blockIdx.x * 128, m0 = blockIdx.y * 128;
  int wm = (wave & 1) * 64, wn = (wave >> 1) * 64;
  f32x4 acc[4][4] = {};
  int sr = t >> 3, sc = (t & 7) * 8;
  float wsc4[4];
  if (!QW) {
    #pragma unroll
    for (int p = 0; p < 4; p++) wsc4[p] = wscale[n0 + p * 32 + sr];
  }
  for (int k0 = 0; k0 < K; k0 += 64) {
    __syncthreads();
    #pragma unroll
    for (int p = 0; p < 4; p++) {
      int r = p * 32 + sr;
      *(int4*)&As[r][sc] = *(const int4*)&A[(size_t)(m0 + r) * K + k0 + sc];
      if (QW) {
        *(int4*)&Ws[r][sc] = *(const int4*)((const __bf16*)W + (size_t)(n0 + r) * K + k0 + sc);
      } else {
        union { bf16x8 v; __bf16 h[8]; } q;
        if (bf) {
          union { int4 v; __bf16 h[8]; } u;
          u.v = *(const int4*)((const __bf16*)W + (size_t)(n0 + r) * K + k0 + sc);
          #pragma unroll
          for (int j = 0; j < 8; j++) q.h[j] = (__bf16)qclamp((float)u.h[j], wsc4[p]);
        } else {
          const float* wp = (const float*)W + (size_t)(n0 + r) * K + k0 + sc;
          float4 a = *(const float4*)wp, b = *(const float4*)(wp + 4);
          q.h[0] = (__bf16)qclamp(a.x, wsc4[p]); q.h[1] = (__bf16)qclamp(a.y, wsc4[p]);
          q.h[2] = (__bf16)qclamp(a.z, wsc4[p]); q.h[3] = (__bf16)qclamp(a.w, wsc4[p]);
          q.h[4] = (__bf16)qclamp(b.x, wsc4[p]); q.h[5] = (__bf16)qclamp(b.y, wsc4[p]);
          q.h[6] = (__bf16)qclamp(b.z, wsc4[p]); q.h[7] = (__bf16)qclamp(b.w, wsc4[p]);
        }
        *(bf16x8*)&Ws[r][sc] = q.v;
      }
    }
    __syncthreads();
    #pragma unroll
    for (int kk = 0; kk < 64; kk += 32) {
      bf16x8 af[4], bfr[4];
      #pragma unroll
      for (int i = 0; i < 4; i++) {
        af[i]  = *(const bf16x8*)&As[wm + i * 16 + l15][kk + quad * 8];
        bfr[i] = *(const bf16x8*)&Ws[wn + i * 16 + l15][kk + quad * 8];
      }
      #pragma unroll
      for (int i = 0; i < 4; i++)
        #pragma unroll
        for (int j = 0; j < 4; j++)
          acc[i][j] = __builtin_amdgcn_mfma_f32_16x16x32_bf16(af[i], bfr[j], acc[i][j], 0, 0, 0);
    }
  }
  float asc = slot_scale(aslot);
  #pragma unroll
  for (int j = 0; j < 4; j++) {
    int gn = n0 + wn + j * 16 + l15;
    float wsb = wscale[gn] * asc;
    float bv = ldin(bias, gn, bf);
    #pragma unroll
    for (int i = 0; i < 4; i++)
      #pragma unroll
      for (int r = 0; r < 4; r++) {
        int gm = m0 + wm + i * 16 + quad * 4 + r;   // C/D: col=lane&15, row=quad*4+reg (m89)
        float val = acc[i][j][r] * wsb + bv;
        if (MODE == 0) {
          ((float*)outp)[(size_t)(gn >> 7) * (SEQ * DH) + (size_t)(off + gm) * DH + (gn & 127)] = val;
        } else {
          size_t idx = (size_t)(off + gm) * DM + gn;
          if (bf) ((__bf16*)outp)[idx] = (__bf16)val; else ((float*)outp)[idx] = val;
        }
      }
  }
}

// ===== Flash attention: Br=128, Bc=64, online softmax =====
// SPLIT=1: grid (18, NH, NSPLIT), each block does 9 KV tiles, writes unnormalized
// partial O + (m,l) per row; flash_combine_k merges. Fixes the measured 12%
// occupancy (288 blocks / 256 CUs) -> 1152 blocks, 3 blocks/CU (LDS-capped).
template<int SPLIT>
__global__ __launch_bounds__(256, 2)
void flash_attn_k(const __bf16* __restrict__ Qb, const __bf16* __restrict__ Kb,
                  const __bf16* __restrict__ Vt, float* __restrict__ O,
                  float* __restrict__ Op, float* __restrict__ Mp, float* __restrict__ Lp) {
  __shared__ __bf16 Ks[64][136];
  __shared__ __bf16 Vs[128][72];
  __shared__ __bf16 Ps[128][72];
  const int t = threadIdx.x, lane = t & 63, wave = t >> 6;
  const int l15 = lane & 15, quad = lane >> 4;
  const int h = blockIdx.y, s0 = blockIdx.x * 128, qr = wave * 32;
  const float fscale = 0.08838834764831845f * 1.4426950408889634f;  // sm_scale*log2e

  bf16x8 qf[2][4];
  #pragma unroll
  for (int mi = 0; mi < 2; mi++)
    #pragma unroll
    for (int kk = 0; kk < 4; kk++)
      qf[mi][kk] = *(const bf16x8*)&Qb[(size_t)(h * SEQ + s0 + qr + mi * 16 + l15) * DH + kk * 32 + quad * 8];

  f32x4 accO[2][8] = {};
  float m_st[2][4], l_st[2][4];
  #pragma unroll
  for (int mi = 0; mi < 2; mi++)
    #pragma unroll
    for (int r = 0; r < 4; r++) { m_st[mi][r] = -1e30f; l_st[mi][r] = 0.f; }

  const int ktb = SPLIT ? blockIdx.z * (SEQ / 64 / NSPLIT) : 0;
  const int kte = SPLIT ? ktb + (SEQ / 64 / NSPLIT) : SEQ / 64;
  for (int kt = ktb; kt < kte; kt++) {
    __syncthreads();
    #pragma unroll
    for (int p = 0; p < 4; p++) {
      int r = p * 16 + (t >> 4), c = (t & 15) * 8;
      *(int4*)&Ks[r][c] = *(const int4*)&Kb[(size_t)(h * SEQ + kt * 64 + r) * DH + c];
    }
    #pragma unroll
    for (int p = 0; p < 4; p++) {
      int r = p * 32 + (t >> 3), c = (t & 7) * 8;
      *(int4*)&Vs[r][c] = *(const int4*)&Vt[(size_t)(h * DH + r) * SEQ + kt * 64 + c];
    }
    __syncthreads();

    f32x4 accS[2][4] = {};
    #pragma unroll
    for (int kk = 0; kk < 4; kk++) {
      bf16x8 bk[4];
      #pragma unroll
      for (int ni = 0; ni < 4; ni++)
        bk[ni] = *(const bf16x8*)&Ks[ni * 16 + l15][kk * 32 + quad * 8];
      #pragma unroll
      for (int mi = 0; mi < 2; mi++)
        #pragma unroll
        for (int ni = 0; ni < 4; ni++)
          accS[mi][ni] = __builtin_amdgcn_mfma_f32_16x16x32_bf16(qf[mi][kk], bk[ni], accS[mi][ni], 0, 0, 0);
    }

    float al[2][4];
    #pragma unroll
    for (int mi = 0; mi < 2; mi++)
      #pragma unroll
      for (int r = 0; r < 4; r++) {
        float rm = fmaxf(fmaxf(accS[mi][0][r], accS[mi][1][r]), fmaxf(accS[mi][2][r], accS[mi][3][r]));
        #pragma unroll
        for (int off = 8; off > 0; off >>= 1) rm = fmaxf(rm, __shfl_xor(rm, off));
        float mn = fmaxf(m_st[mi][r], rm);
        al[mi][r] = exp2f((m_st[mi][r] - mn) * fscale);
        m_st[mi][r] = mn;
      }
    #pragma unroll
    for (int mi = 0; mi < 2; mi++)
      #pragma unroll
      for (int r = 0; r < 4; r++) {
        float rs = 0.f;
        #pragma unroll
        for (int ni = 0; ni < 4; ni++) {
          float pv = exp2f((accS[mi][ni][r] - m_st[mi][r]) * fscale);
          accS[mi][ni][r] = pv;
          rs += pv;
        }
        #pragma unroll
        for (int off = 8; off > 0; off >>= 1) rs += __shfl_xor(rs, off);
        l_st[mi][r] = l_st[mi][r] * al[mi][r] + rs;
      }
    #pragma unroll
    for (int mi = 0; mi < 2; mi++)
      #pragma unroll
      for (int di = 0; di < 8; di++)
        #pragma unroll
        for (int r = 0; r < 4; r++)
          accO[mi][di][r] *= al[mi][r];
    #pragma unroll
    for (int mi = 0; mi < 2; mi++)
      #pragma unroll
      for (int ni = 0; ni < 4; ni++)
        #pragma unroll
        for (int r = 0; r < 4; r++)
          Ps[qr + mi * 16 + quad * 4 + r][ni * 16 + l15] = (__bf16)accS[mi][ni][r];
    __syncthreads();
    #pragma unroll
    for (int kk2 = 0; kk2 < 2; kk2++) {
      bf16x8 pa[2], vb[8];
      #pragma unroll
      for (int mi = 0; mi < 2; mi++)
        pa[mi] = *(const bf16x8*)&Ps[qr + mi * 16 + l15][kk2 * 32 + quad * 8];
      #pragma unroll
      for (int di = 0; di < 8; di++)
        vb[di] = *(const bf16x8*)&Vs[di * 16 + l15][kk2 * 32 + quad * 8];
      #pragma unroll
      for (int mi = 0; mi < 2; mi++)
        #pragma unroll
        for (int di = 0; di < 8; di++)
          accO[mi][di] = __builtin_amdgcn_mfma_f32_16x16x32_bf16(pa[mi], vb[di], accO[mi][di], 0, 0, 0);
    }
  }
  if (SPLIT) {
    const size_t SP = (size_t)NH * SEQ * DH;
    const int sp = blockIdx.z;
    #pragma unroll
    for (int mi = 0; mi < 2; mi++)
      #pragma unroll
      for (int r = 0; r < 4; r++) {
        int gs = s0 + qr + mi * 16 + quad * 4 + r;
        size_t ib = sp * SP + ((size_t)h * SEQ + gs) * DH;
        if (l15 == 0) {
          Mp[(size_t)sp * NH * SEQ + h * SEQ + gs] = m_st[mi][r];
          Lp[(size_t)sp * NH * SEQ + h * SEQ + gs] = l_st[mi][r];
        }
        #pragma unroll
        for (int di = 0; di < 8; di++)
          Op[ib + di * 16 + l15] = accO[mi][di][r];
      }
  } else {
    #pragma unroll
    for (int mi = 0; mi < 2; mi++)
      #pragma unroll
      for (int r = 0; r < 4; r++) {
        float inv = 1.0f / l_st[mi][r];
        int gs = s0 + qr + mi * 16 + quad * 4 + r;
        #pragma unroll
        for (int di = 0; di < 8; di++)
          O[(size_t)gs * DM + h * DH + di * 16 + l15] = accO[mi][di][r] * inv;
      }
  }
}

// Merge NSPLIT partials: one wave per row, 2 d-elements per lane.
__global__ void flash_combine_k(const float* __restrict__ Op, const float* __restrict__ Mp,
                                const float* __restrict__ Lp, float* __restrict__ O) {
  const float fscale = 0.08838834764831845f * 1.4426950408889634f;
  const int t = threadIdx.x, lane = t & 63, w = t >> 6;   // 16 waves (1024 thr)
  const size_t SP = (size_t)NH * SEQ * DH, MR = (size_t)NH * SEQ;
  for (int row = blockIdx.x * 16 + w; row < NH * SEQ; row += gridDim.x * 16) {
    float m0 = Mp[row], m1 = Mp[MR + row], m2 = Mp[2 * MR + row], m3 = Mp[3 * MR + row];
    float M = fmaxf(fmaxf(m0, m1), fmaxf(m2, m3));
    float w0 = exp2f((m0 - M) * fscale), w1 = exp2f((m1 - M) * fscale);
    float w2 = exp2f((m2 - M) * fscale), w3 = exp2f((m3 - M) * fscale);
    float inv = 1.0f / (Lp[row] * w0 + Lp[MR + row] * w1 + Lp[2 * MR + row] * w2 + Lp[3 * MR + row] * w3);
    int h = row / SEQ, s = row % SEQ;
    size_t ob = (size_t)s * DM + h * DH, ib = (size_t)row * DH;
    #pragma unroll
    for (int j = 0; j < 2; j++) {
      int d = lane + j * 64;
      float v = Op[ib + d] * w0 + Op[SP + ib + d] * w1 + Op[2 * SP + ib + d] * w2 + Op[3 * SP + ib + d] * w3;
      O[ob + d] = v * inv;
    }
  }
}

extern "C" void kernel_launch(void* const* d_in, const int* in_sizes, int n_in,
                              void* d_out, int out_size, void* d_ws, size_t ws_size,
                              hipStream_t stream) {
  (void)in_sizes; (void)n_in; (void)out_size;
  const void* hs   = d_in[0];
  const void* es   = d_in[1];
  const void* cosb = d_in[2];
  const void* sinb = d_in[3];
  const void* W[8]; const void* Bv[8];
  for (int i = 0; i < 8; i++) { W[i] = d_in[4 + 2 * i]; Bv[i] = d_in[5 + 2 * i]; }
  const void* nq  = d_in[20];
  const void* nk  = d_in[21];
  const void* naq = d_in[22];
  const void* nak = d_in[23];

  char* ws = (char*)d_ws;
  size_t off = 0;
  auto take = [&](size_t b) { char* p = ws + off; off += (b + 255) & ~(size_t)255; return p; };
  unsigned* slots = (unsigned*)take(64);
  int* flagp = (int*)((char*)slots + 48);
  float*  wsc  = (float*)take(8ull * DM * 4);
  char*   bufA = take((size_t)SEQ * DM * 2);                // hq+eq, later attnq
  __bf16* hq    = (__bf16*)bufA;
  __bf16* eq    = (__bf16*)(bufA + (size_t)L_IMG * DM * 2);
  __bf16* attnq = (__bf16*)bufA;
  float*  qkvf  = (float*)take((size_t)NH * SEQ * DH * 4);  // later attnf
  float*  attnf = qkvf;
  __bf16* qb  = (__bf16*)take((size_t)NH * SEQ * DH * 2);
  __bf16* kb  = (__bf16*)take((size_t)NH * SEQ * DH * 2);
  __bf16* vtb = (__bf16*)take((size_t)NH * SEQ * DH * 2);
  // base ends ~57 MB. Optional groups, gated on ws_size:
  const size_t need_split = ((size_t)NSPLIT * NH * SEQ * DH * 4 + 512) +
                            2 * ((size_t)NSPLIT * NH * SEQ * 4 + 512);
  bool do_split = (off + need_split <= ws_size);
  float *Opart = nullptr, *Mpart = nullptr, *Lpart = nullptr;
  if (do_split) {
    Opart = (float*)take((size_t)NSPLIT * NH * SEQ * DH * 4);
    Mpart = (float*)take((size_t)NSPLIT * NH * SEQ * 4);
    Lpart = (float*)take((size_t)NSPLIT * NH * SEQ * 4);
  }
  const size_t need_wq = 8ull * DM * DM * 2 + 512;
  bool do_prequant = (off + need_wq <= ws_size);
  __bf16* wq = nullptr;
  if (do_prequant) wq = (__bf16*)take(8ull * DM * DM * 2);

  hipMemsetAsync(slots, 0, 64, stream);
  detect_k<<<1, 64, 0, stream>>>(cosb, flagp);

  Ptrs8 win;
  for (int i = 0; i < 8; i++) win.p[i] = W[i];
  if (do_prequant)
    quant_weights_k<<<dim3(DM, 8), 256, 0, stream>>>(win, wq, wsc, flagp);
  else
    weight_scales_k<<<dim3(DM, 8), 256, 0, stream>>>(win, wsc, flagp);

  absmax_in_k<<<256, 256, 0, stream>>>(hs, L_IMG * DM, slots + 0, flagp);
  absmax_in_k<<<256, 256, 0, stream>>>(es, L_TXT * DM, slots + 1, flagp);
  quant_int_in_k<<<L_IMG * DM / 256, 256, 0, stream>>>(hs, L_IMG * DM, slots + 0, hq, flagp);
  quant_int_in_k<<<L_TXT * DM / 256, 256, 0, stream>>>(es, L_TXT * DM, slots + 1, eq, flagp);

  auto gemm0 = [&](const __bf16* A, int mat, const unsigned* aslot, void* out, int o, dim3 grid) {
    if (do_prequant)
      gemm_bt<0, 1><<<grid, 256, 0, stream>>>(A, wq + (size_t)mat * DM * DM, wsc + mat * DM,
                                              aslot, Bv[mat], out, flagp, o);
    else
      gemm_bt<0, 0><<<grid, 256, 0, stream>>>(A, W[mat], wsc + mat * DM,
                                              aslot, Bv[mat], out, flagp, o);
  };
  auto gemm1 = [&](const __bf16* A, int mat, const unsigned* aslot, void* out, int o, dim3 grid) {
    if (do_prequant)
      gemm_bt<1, 1><<<grid, 256, 0, stream>>>(A, wq + (size_t)mat * DM * DM, wsc + mat * DM,
                                              aslot, Bv[mat], out, flagp, o);
    else
      gemm_bt<1, 0><<<grid, 256, 0, stream>>>(A, W[mat], wsc + mat * DM,
                                              aslot, Bv[mat], out, flagp, o);
  };

  for (int tns = 0; tns < 3; tns++) {
    gemm0(hq, tns, slots + 0, qkvf, L_TXT, dim3(16, 16));
    gemm0(eq, 3 + tns, slots + 1, qkvf, 0, dim3(16, 2));
    if (tns == 0) {
      rmsnorm_absmax_k<<<256, 1024, 0, stream>>>(qkvf, nq, naq, slots + 2, slots + 3, flagp);
      quant_rope_k<<<NH * SEQ * 64 / 256, 256, 0, stream>>>(qkvf, cosb, sinb, slots + 2, slots + 3, qb, flagp);
    } else if (tns == 1) {
      rmsnorm_absmax_k<<<256, 1024, 0, stream>>>(qkvf, nk, nak, slots + 4, slots + 5, flagp);
      quant_rope_k<<<NH * SEQ * 64 / 256, 256, 0, stream>>>(qkvf, cosb, sinb, slots + 4, slots + 5, kb, flagp);
    } else {
      absmax_v_k<<<256, 256, 0, stream>>>(qkvf, slots + 6, slots + 7);
      quant_transpose_v_k<<<dim3(SEQ / 64, DH / 64, NH), 256, 0, stream>>>(qkvf, slots + 6, slots + 7, vtb);
    }
  }

  if (do_split) {
    flash_attn_k<1><<<dim3(SEQ / 128, NH, NSPLIT), 256, 0, stream>>>(qb, kb, vtb, nullptr,
                                                                     Opart, Mpart, Lpart);
    flash_combine_k<<<576, 1024, 0, stream>>>(Opart, Mpart, Lpart, attnf);
  } else {
    flash_attn_k<0><<<dim3(SEQ / 128, NH), 256, 0, stream>>>(qb, kb, vtb, attnf,
                                                             nullptr, nullptr, nullptr);
  }

  absmax_f32_k<<<256, 256, 0, stream>>>(attnf, SEQ * DM, slots + 8);
  quant_int_f32_k<<<SEQ * DM / 256, 256, 0, stream>>>(attnf, SEQ * DM, slots + 8, attnq);

  gemm1(attnq + (size_t)L_TXT * DM, 6, slots + 8, d_out, 0, dim3(16, 16));
  gemm1(attnq, 7, slots + 8, d_out, L_IMG, dim3(16, 2));
}

// Round 5
// 830.174 us; speedup vs baseline: 2.9694x; 1.1562x over previous
//
#include <hip/hip_runtime.h>

// ===== Problem constants =====
constexpr int L_TXT = 256, L_IMG = 2048, SEQ = 2304;
constexpr int DM = 2048, NH = 16, DH = 128;
constexpr int NSPLIT = 4;      // flash split-K factor
constexpr int SSTR = 32;       // slot stride in unsigneds (128 B) - avoids atomic cacheline ping-pong

typedef __attribute__((ext_vector_type(8))) __bf16 bf16x8;
typedef __attribute__((ext_vector_type(4))) float f32x4;

// Runtime dtype flag: 0 = fp32 storage, 1 = bf16 (detected from rope_cos[0]).
__device__ __forceinline__ float ldin(const void* p, size_t i, int bf) {
  return bf ? (float)((const __bf16*)p)[i] : ((const float*)p)[i];
}
__device__ __forceinline__ float slot_scale(const unsigned* s) {
  return fmaxf(__uint_as_float(*s) / 127.0f, 1e-8f);
}
__device__ __forceinline__ float qclamp(float x, float sc) {
  float q = rintf(x / sc);     // RNE, matches jnp.round
  return fminf(fmaxf(q, -127.0f), 127.0f);
}
__device__ __forceinline__ float block_allmax_n(float v) {  // any blockDim multiple of 64 (<=1024)
  #pragma unroll
  for (int off = 32; off; off >>= 1) v = fmaxf(v, __shfl_xor(v, off));
  __shared__ float sm[16];
  int nw = blockDim.x >> 6;
  __syncthreads();
  if ((threadIdx.x & 63) == 0) sm[threadIdx.x >> 6] = v;
  __syncthreads();
  float m = sm[0];
  for (int i = 1; i < nw; i++) m = fmaxf(m, sm[i]);
  return m;
}

__global__ void detect_k(const void* cosp, int* flag) {
  if (threadIdx.x == 0) *flag = (((const unsigned short*)cosp)[0] != 0) ? 1 : 0;
}

struct Ptrs8 { const void* p[8]; };

// ===== Weight quantization (vectorized): scales + int-grid bf16 weights =====
__global__ void quant_weights_k(Ptrs8 win, __bf16* __restrict__ wq, float* __restrict__ scales,
                                const int* __restrict__ flagp) {
  const int bf = *flagp;
  int row = blockIdx.x, mat = blockIdx.y, t = threadIdx.x;
  float v[8];
  if (bf) {
    union { int4 q; __bf16 h[8]; } u;
    u.q = ((const int4*)((const __bf16*)win.p[mat] + (size_t)row * DM))[t];
    #pragma unroll
    for (int j = 0; j < 8; j++) v[j] = (float)u.h[j];
  } else {
    const float4* p = (const float4*)((const float*)win.p[mat] + (size_t)row * DM);
    float4 a = p[t * 2], b = p[t * 2 + 1];
    v[0]=a.x; v[1]=a.y; v[2]=a.z; v[3]=a.w; v[4]=b.x; v[5]=b.y; v[6]=b.z; v[7]=b.w;
  }
  float m = 0.f;
  #pragma unroll
  for (int j = 0; j < 8; j++) m = fmaxf(m, fabsf(v[j]));
  m = block_allmax_n(m);
  float sc = fmaxf(m / 127.0f, 1e-8f);
  if (t == 0) scales[mat * DM + row] = sc;
  union { int4 q; __bf16 h[8]; } o;
  #pragma unroll
  for (int j = 0; j < 8; j++) o.h[j] = (__bf16)qclamp(v[j], sc);
  ((int4*)(wq + (size_t)mat * DM * DM + (size_t)row * DM))[t] = o.q;
}
// fallback: scales only
__global__ void weight_scales_k(Ptrs8 win, float* __restrict__ scales, const int* __restrict__ flagp) {
  const int bf = *flagp;
  int row = blockIdx.x, mat = blockIdx.y, t = threadIdx.x;
  float m = 0.f;
  for (int c = t; c < DM; c += 256) m = fmaxf(m, fabsf(ldin(win.p[mat], (size_t)row * DM + c, bf)));
  m = block_allmax_n(m);
  if (t == 0) scales[mat * DM + row] = fmaxf(m / 127.0f, 1e-8f);
}

// ===== absmax of hidden + encoder in one pass (vectorized x8) =====
__global__ void absmax_he_k(const void* __restrict__ hs, const void* __restrict__ es,
                            unsigned* s0, unsigned* s1, const int* __restrict__ flagp) {
  const int bf = *flagp;
  const int n18 = L_IMG * DM / 8, n28 = L_TXT * DM / 8;
  float m1 = 0.f, m2 = 0.f;
  for (int i = blockIdx.x * 256 + threadIdx.x; i < n18 + n28; i += gridDim.x * 256) {
    bool h = i < n18;
    const void* src = h ? hs : es;
    int j = h ? i : i - n18;
    float lm = 0.f;
    if (bf) {
      union { int4 q; __bf16 x[8]; } u; u.q = ((const int4*)src)[j];
      #pragma unroll
      for (int k = 0; k < 8; k++) lm = fmaxf(lm, fabsf((float)u.x[k]));
    } else {
      const float4* p = (const float4*)src;
      float4 a = p[j * 2], b = p[j * 2 + 1];
      lm = fmaxf(fmaxf(fmaxf(fabsf(a.x), fabsf(a.y)), fmaxf(fabsf(a.z), fabsf(a.w))),
                 fmaxf(fmaxf(fabsf(b.x), fabsf(b.y)), fmaxf(fabsf(b.z), fabsf(b.w))));
    }
    if (h) m1 = fmaxf(m1, lm); else m2 = fmaxf(m2, lm);
  }
  m1 = block_allmax_n(m1);
  __syncthreads();
  m2 = block_allmax_n(m2);
  if (threadIdx.x == 0) { atomicMax(s0, __float_as_uint(m1)); atomicMax(s1, __float_as_uint(m2)); }
}

// ===== quantize hidden+encoder to int-grid bf16 (vectorized x8) =====
__global__ void quant_he_k(const void* __restrict__ hs, const void* __restrict__ es,
                           const unsigned* __restrict__ slots, __bf16* __restrict__ hqo,
                           __bf16* __restrict__ eqo, const int* __restrict__ flagp) {
  const int bf = *flagp;
  const int n18 = L_IMG * DM / 8, n28 = L_TXT * DM / 8;
  float sc0 = slot_scale(slots), sc1 = slot_scale(slots + SSTR);
  for (int i = blockIdx.x * 256 + threadIdx.x; i < n18 + n28; i += gridDim.x * 256) {
    bool h = i < n18;
    const void* src = h ? hs : es;
    int j = h ? i : i - n18;
    float sc = h ? sc0 : sc1;
    float v[8];
    if (bf) {
      union { int4 q; __bf16 x[8]; } u; u.q = ((const int4*)src)[j];
      #pragma unroll
      for (int k = 0; k < 8; k++) v[k] = (float)u.x[k];
    } else {
      const float4* p = (const float4*)src;
      float4 a = p[j * 2], b = p[j * 2 + 1];
      v[0]=a.x; v[1]=a.y; v[2]=a.z; v[3]=a.w; v[4]=b.x; v[5]=b.y; v[6]=b.z; v[7]=b.w;
    }
    union { int4 q; __bf16 x[8]; } o;
    #pragma unroll
    for (int k = 0; k < 8; k++) o.x[k] = (__bf16)qclamp(v[k], sc);
    ((int4*)(h ? hqo : eqo))[j] = o.q;
  }
}

// ===== quantize fp32 attn-out to int-grid bf16 (vectorized x8) =====
__global__ void quant_f32x8_k(const float* __restrict__ x, int n8,
                              const unsigned* __restrict__ slot, __bf16* __restrict__ out) {
  float sc = slot_scale(slot);
  for (int i = blockIdx.x * 256 + threadIdx.x; i < n8; i += gridDim.x * 256) {
    float4 a = ((const float4*)x)[i * 2], b = ((const float4*)x)[i * 2 + 1];
    union { int4 q; __bf16 h[8]; } o;
    o.h[0]=(__bf16)qclamp(a.x,sc); o.h[1]=(__bf16)qclamp(a.y,sc);
    o.h[2]=(__bf16)qclamp(a.z,sc); o.h[3]=(__bf16)qclamp(a.w,sc);
    o.h[4]=(__bf16)qclamp(b.x,sc); o.h[5]=(__bf16)qclamp(b.y,sc);
    o.h[6]=(__bf16)qclamp(b.z,sc); o.h[7]=(__bf16)qclamp(b.w,sc);
    ((int4*)out)[i] = o.q;
  }
}
// fallback absmax (non-split flash path)
__global__ void absmax_f32_k(const float* __restrict__ x, int n, unsigned* slot) {
  float m = 0.f;
  for (int i = blockIdx.x * 256 + threadIdx.x; i < n; i += gridDim.x * 256)
    m = fmaxf(m, fabsf(x[i]));
  m = block_allmax_n(m);
  if (threadIdx.x == 0) atomicMax(slot, __float_as_uint(m));
}

// ===== fused: rmsnorm(q)+absmax, rmsnorm(k)+absmax, absmax(v) =====
__global__ void rms_absmax_v_k(float* __restrict__ qf, float* __restrict__ kf, float* __restrict__ vf,
                               const void* nq, const void* naq, const void* nk, const void* nak,
                               unsigned* __restrict__ slots, const int* __restrict__ flagp) {
  const int bf = *flagp;
  const int t = threadIdx.x, lane = t & 63, wave = t >> 6;   // 1024 thr = 16 waves
  float wqt0 = ldin(naq, lane, bf), wqt1 = ldin(naq, lane + 64, bf);
  float wqi0 = ldin(nq,  lane, bf), wqi1 = ldin(nq,  lane + 64, bf);
  float wkt0 = ldin(nak, lane, bf), wkt1 = ldin(nak, lane + 64, bf);
  float wki0 = ldin(nk,  lane, bf), wki1 = ldin(nk,  lane + 64, bf);
  const int NR = NH * SEQ;
  float mx[6] = {0.f, 0.f, 0.f, 0.f, 0.f, 0.f};
  for (int row = blockIdx.x * 16 + wave; row < 3 * NR; row += gridDim.x * 16) {
    int tns = row / NR, r2 = row - tns * NR;
    int s = r2 % SEQ; bool txt = s < L_TXT;
    float* p = (tns == 0 ? qf : tns == 1 ? kf : vf) + (size_t)r2 * DH;
    float v0 = p[lane], v1 = p[lane + 64];
    if (tns < 2) {
      float ss = v0 * v0 + v1 * v1;
      #pragma unroll
      for (int off = 32; off; off >>= 1) ss += __shfl_xor(ss, off);
      float r = rsqrtf(ss * (1.0f / 128.0f) + 1e-6f);
      float w0, w1;
      if (tns == 0) { w0 = txt ? wqt0 : wqi0; w1 = txt ? wqt1 : wqi1; }
      else          { w0 = txt ? wkt0 : wki0; w1 = txt ? wkt1 : wki1; }
      v0 *= r * w0; v1 *= r * w1;
      p[lane] = v0; p[lane + 64] = v1;
    }
    int idx = tns * 2 + (txt ? 0 : 1);
    mx[idx] = fmaxf(mx[idx], fmaxf(fabsf(v0), fabsf(v1)));
  }
  #pragma unroll
  for (int off = 32; off; off >>= 1)
    #pragma unroll
    for (int j = 0; j < 6; j++) mx[j] = fmaxf(mx[j], __shfl_xor(mx[j], off));
  __shared__ float smx[16][6];
  if (lane == 0)
    #pragma unroll
    for (int j = 0; j < 6; j++) smx[wave][j] = mx[j];
  __syncthreads();
  if (t == 0) {
    #pragma unroll
    for (int j = 0; j < 6; j++) {
      float m = smx[0][j];
      for (int i = 1; i < 16; i++) m = fmaxf(m, smx[i][j]);
      atomicMax(slots + (2 + j) * SSTR, __float_as_uint(m));
    }
  }
}

// ===== fused rope for q and k: quantize (dequant) + rotate + bf16 =====
__global__ void rope2_k(const float* __restrict__ qf, const float* __restrict__ kf,
                        const void* cosb, const void* sinb, const unsigned* __restrict__ slots,
                        __bf16* __restrict__ qb, __bf16* __restrict__ kb, const int* __restrict__ flagp) {
  const int bf = *flagp;
  const int NP = NH * SEQ * 64;
  for (int i = blockIdx.x * 256 + threadIdx.x; i < 2 * NP; i += gridDim.x * 256) {
    int tns = i >= NP;
    int j = i - tns * NP;
    int pr = j & 63, rowg = j >> 6;
    int s = rowg % SEQ;
    const float* src = tns ? kf : qf;
    __bf16* dst = tns ? kb : qb;
    float sc = slot_scale(slots + (tns ? 4 : 2) * SSTR + (s < L_TXT ? 0 : SSTR));
    size_t base = (size_t)rowg * DH + pr * 2;
    float2 x2 = *(const float2*)(src + base);
    float q0 = qclamp(x2.x, sc) * sc, q1 = qclamp(x2.y, sc) * sc;
    float c0 = ldin(cosb, s * DH + 2 * pr, bf), c1 = ldin(cosb, s * DH + 2 * pr + 1, bf);
    float s0 = ldin(sinb, s * DH + 2 * pr, bf), s1 = ldin(sinb, s * DH + 2 * pr + 1, bf);
    dst[base]     = (__bf16)(q0 * c0 - q1 * s0);
    dst[base + 1] = (__bf16)(q1 * c1 + q0 * s1);
  }
}

// ===== V: quantize + transpose [NH][SEQ][DH] -> [NH][DH][SEQ] =====
__global__ void quant_transpose_v_k(const float* __restrict__ v, const unsigned* __restrict__ slots,
                                    __bf16* __restrict__ vt) {
  __shared__ float tile[64][65];
  int t = threadIdx.x;
  int s0 = blockIdx.x * 64, d0 = blockIdx.y * 64, h = blockIdx.z;
  #pragma unroll
  for (int i = 0; i < 16; i++) {
    int r = i * 4 + (t >> 6), c = t & 63;
    tile[r][c] = v[((size_t)(h * SEQ) + s0 + r) * DH + d0 + c];
  }
  __syncthreads();
  float sc = slot_scale(slots + (s0 < L_TXT ? 6 : 7) * SSTR);
  #pragma unroll
  for (int i = 0; i < 16; i++) {
    int d = i * 4 + (t >> 6), s = t & 63;
    float q = qclamp(tile[s][d], sc) * sc;
    vt[((size_t)(h * DH) + d0 + d) * SEQ + s0 + s] = (__bf16)q;
  }
}

// ===== GEMM (fused launches) =====
// MODE 0: QKV. grid (16, 18, 3): y<2 txt (A=eq, mats 3..5), else img (A=hq, mats 0..2).
//         Writes fp32 head-split [h][s][d] into outs[z], s = y*128+gm.
// MODE 1: out-proj. grid (16, 18): y<16 img (A=attnq img rows, mat 6), else txt (mat 7).
//         Writes d_out (dtype per flag).
struct GemmArgs {
  const __bf16 *hq, *eq, *attnq;
  const __bf16* wqp;
  const void* Wraw[8];
  const float* wsc;
  const void* bias[8];
  float* outs[3];
  void* dout;
  const unsigned* slots;
  const int* flagp;
};
template<int MODE, int QW>
__global__ __launch_bounds__(256, 2)
void gemm_f(GemmArgs a) {
  const int bf = *a.flagp;
  constexpr int K = DM;
  __shared__ __bf16 As[128][72];
  __shared__ __bf16 Ws[128][72];
  const int t = threadIdx.x, lane = t & 63, wave = t >> 6;
  const int l15 = lane & 15, quad = lane >> 4;
  const int n0 = blockIdx.x * 128, y = blockIdx.y;
  int mat, outrow; const __bf16* A; const unsigned* aslot;
  if (MODE == 0) {
    bool txt = y < 2;
    mat = blockIdx.z + (txt ? 3 : 0);
    A = (txt ? a.eq : a.hq) + (size_t)(txt ? y * 128 : (y - 2) * 128) * K;
    outrow = y * 128;
    aslot = a.slots + (txt ? SSTR : 0);
  } else {
    bool img = y < 16;
    mat = img ? 6 : 7;
    A = a.attnq + (size_t)(img ? L_TXT + y * 128 : (y - 16) * 128) * K;
    outrow = img ? y * 128 : L_IMG + (y - 16) * 128;
    aslot = a.slots + 8 * SSTR;
  }
  const __bf16* Wq = QW ? a.wqp + (size_t)mat * DM * DM : nullptr;
  const void* Wr = a.Wraw[mat];
  const float* wrow = a.wsc + mat * DM;
  int wm = (wave & 1) * 64, wn = (wave >> 1) * 64;
  f32x4 acc[4][4] = {};
  int sr = t >> 3, sc = (t & 7) * 8;
  float wsc4[4];
  if (!QW) {
    #pragma unroll
    for (int p = 0; p < 4; p++) wsc4[p] = wrow[n0 + p * 32 + sr];
  }
  for (int k0 = 0; k0 < K; k0 += 64) {
    __syncthreads();
    #pragma unroll
    for (int p = 0; p < 4; p++) {
      int r = p * 32 + sr;
      *(int4*)&As[r][sc] = *(const int4*)&A[(size_t)r * K + k0 + sc];
      if (QW) {
        *(int4*)&Ws[r][sc] = *(const int4*)&Wq[(size_t)(n0 + r) * K + k0 + sc];
      } else {
        union { bf16x8 v; __bf16 h[8]; } q;
        if (bf) {
          union { int4 v; __bf16 h[8]; } u;
          u.v = *(const int4*)((const __bf16*)Wr + (size_t)(n0 + r) * K + k0 + sc);
          #pragma unroll
          for (int j = 0; j < 8; j++) q.h[j] = (__bf16)qclamp((float)u.h[j], wsc4[p]);
        } else {
          const float* wp = (const float*)Wr + (size_t)(n0 + r) * K + k0 + sc;
          float4 x = *(const float4*)wp, z = *(const float4*)(wp + 4);
          q.h[0]=(__bf16)qclamp(x.x,wsc4[p]); q.h[1]=(__bf16)qclamp(x.y,wsc4[p]);
          q.h[2]=(__bf16)qclamp(x.z,wsc4[p]); q.h[3]=(__bf16)qclamp(x.w,wsc4[p]);
          q.h[4]=(__bf16)qclamp(z.x,wsc4[p]); q.h[5]=(__bf16)qclamp(z.y,wsc4[p]);
          q.h[6]=(__bf16)qclamp(z.z,wsc4[p]); q.h[7]=(__bf16)qclamp(z.w,wsc4[p]);
        }
        *(bf16x8*)&Ws[r][sc] = q.v;
      }
    }
    __syncthreads();
    #pragma unroll
    for (int kk = 0; kk < 64; kk += 32) {
      bf16x8 af[4], bfr[4];
      #pragma unroll
      for (int i = 0; i < 4; i++) {
        af[i]  = *(const bf16x8*)&As[wm + i * 16 + l15][kk + quad * 8];
        bfr[i] = *(const bf16x8*)&Ws[wn + i * 16 + l15][kk + quad * 8];
      }
      #pragma unroll
      for (int i = 0; i < 4; i++)
        #pragma unroll
        for (int j = 0; j < 4; j++)
          acc[i][j] = __builtin_amdgcn_mfma_f32_16x16x32_bf16(af[i], bfr[j], acc[i][j], 0, 0, 0);
    }
  }
  float asc = slot_scale(aslot);
  #pragma unroll
  for (int j = 0; j < 4; j++) {
    int gn = n0 + wn + j * 16 + l15;
    float wsb = wrow[gn] * asc;
    float bv = ldin(a.bias[mat], gn, bf);
    #pragma unroll
    for (int i = 0; i < 4; i++)
      #pragma unroll
      for (int r = 0; r < 4; r++) {
        int gm = wm + i * 16 + quad * 4 + r;    // C/D: col=lane&15, row=quad*4+reg (m89)
        float val = acc[i][j][r] * wsb + bv;
        if (MODE == 0) {
          a.outs[blockIdx.z][(size_t)(gn >> 7) * (SEQ * DH) + (size_t)(outrow + gm) * DH + (gn & 127)] = val;
        } else {
          size_t idx = (size_t)(outrow + gm) * DM + gn;
          if (bf) ((__bf16*)a.dout)[idx] = (__bf16)val; else ((float*)a.dout)[idx] = val;
        }
      }
  }
}

// ===== Flash attention: Br=128, Bc=64, online softmax, Ps aliases Ks =====
// LDS: Ks 64x152 (19456 B, reused as Ps 128x72 after QK^T) + Vs 128x72 (18432 B)
// = 37888 B -> 4 blocks/CU (round-4 fix: was 54 KB -> 2 blocks/CU, measured 17.8% occ).
template<int SPLIT>
__global__ __launch_bounds__(256, 4)
void flash_attn_k(const __bf16* __restrict__ Qb, const __bf16* __restrict__ Kb,
                  const __bf16* __restrict__ Vt, float* __restrict__ O,
                  float* __restrict__ Op, float* __restrict__ Mp, float* __restrict__ Lp) {
  __shared__ __align__(16) char smem[19456 + 18432];
  auto Ks = (__bf16(*)[152])smem;            // 64 rows, stride 304 B (16-aligned)
  auto Ps = (__bf16(*)[72])smem;             // 128 rows, stride 144 B — aliases Ks
  auto Vs = (__bf16(*)[72])(smem + 19456);   // 128 rows [d][kc]
  const int t = threadIdx.x, lane = t & 63, wave = t >> 6;
  const int l15 = lane & 15, quad = lane >> 4;
  const int h = blockIdx.y, s0 = blockIdx.x * 128, qr = wave * 32;
  const float fscale = 0.08838834764831845f * 1.4426950408889634f;  // sm_scale*log2e

  bf16x8 qf[2][4];
  #pragma unroll
  for (int mi = 0; mi < 2; mi++)
    #pragma unroll
    for (int kk = 0; kk < 4; kk++)
      qf[mi][kk] = *(const bf16x8*)&Qb[(size_t)(h * SEQ + s0 + qr + mi * 16 + l15) * DH + kk * 32 + quad * 8];

  f32x4 accO[2][8] = {};
  float m_st[2][4], l_st[2][4];
  #pragma unroll
  for (int mi = 0; mi < 2; mi++)
    #pragma unroll
    for (int r = 0; r < 4; r++) { m_st[mi][r] = -1e30f; l_st[mi][r] = 0.f; }

  const int ktb = SPLIT ? blockIdx.z * (SEQ / 64 / NSPLIT) : 0;
  const int kte = SPLIT ? ktb + (SEQ / 64 / NSPLIT) : SEQ / 64;
  for (int kt = ktb; kt < kte; kt++) {
    __syncthreads();   // B1: prior PV reads of Vs/Ps done before restaging
    #pragma unroll
    for (int p = 0; p < 4; p++) {
      int r = p * 16 + (t >> 4), c = (t & 15) * 8;
      *(int4*)&Ks[r][c] = *(const int4*)&Kb[(size_t)(h * SEQ + kt * 64 + r) * DH + c];
    }
    #pragma unroll
    for (int p = 0; p < 4; p++) {
      int r = p * 32 + (t >> 3), c = (t & 7) * 8;
      *(int4*)&Vs[r][c] = *(const int4*)&Vt[(size_t)(h * DH + r) * SEQ + kt * 64 + c];
    }
    __syncthreads();   // B2: staging visible

    f32x4 accS[2][4] = {};
    #pragma unroll
    for (int kk = 0; kk < 4; kk++) {
      bf16x8 bk[4];
      #pragma unroll
      for (int ni = 0; ni < 4; ni++)
        bk[ni] = *(const bf16x8*)&Ks[ni * 16 + l15][kk * 32 + quad * 8];
      #pragma unroll
      for (int mi = 0; mi < 2; mi++)
        #pragma unroll
        for (int ni = 0; ni < 4; ni++)
          accS[mi][ni] = __builtin_amdgcn_mfma_f32_16x16x32_bf16(qf[mi][kk], bk[ni], accS[mi][ni], 0, 0, 0);
    }

    float al[2][4];
    #pragma unroll
    for (int mi = 0; mi < 2; mi++)
      #pragma unroll
      for (int r = 0; r < 4; r++) {
        float rm = fmaxf(fmaxf(accS[mi][0][r], accS[mi][1][r]), fmaxf(accS[mi][2][r], accS[mi][3][r]));
        #pragma unroll
        for (int off = 8; off > 0; off >>= 1) rm = fmaxf(rm, __shfl_xor(rm, off));
        float mn = fmaxf(m_st[mi][r], rm);
        al[mi][r] = exp2f((m_st[mi][r] - mn) * fscale);
        m_st[mi][r] = mn;
      }
    #pragma unroll
    for (int mi = 0; mi < 2; mi++)
      #pragma unroll
      for (int r = 0; r < 4; r++) {
        float rs = 0.f;
        #pragma unroll
        for (int ni = 0; ni < 4; ni++) {
          float pv = exp2f((accS[mi][ni][r] - m_st[mi][r]) * fscale);
          accS[mi][ni][r] = pv;
          rs += pv;
        }
        #pragma unroll
        for (int off = 8; off > 0; off >>= 1) rs += __shfl_xor(rs, off);
        l_st[mi][r] = l_st[mi][r] * al[mi][r] + rs;
      }
    #pragma unroll
    for (int mi = 0; mi < 2; mi++)
      #pragma unroll
      for (int di = 0; di < 8; di++)
        #pragma unroll
        for (int r = 0; r < 4; r++)
          accO[mi][di][r] *= al[mi][r];
    __syncthreads();   // B3: all waves' Ks reads done before P overwrites the alias
    #pragma unroll
    for (int mi = 0; mi < 2; mi++)
      #pragma unroll
      for (int ni = 0; ni < 4; ni++)
        #pragma unroll
        for (int r = 0; r < 4; r++)
          Ps[qr + mi * 16 + quad * 4 + r][ni * 16 + l15] = (__bf16)accS[mi][ni][r];
    // PV: Ps rows are wave-private (lgkmcnt handles RAW); Vs stable since B2
    #pragma unroll
    for (int kk2 = 0; kk2 < 2; kk2++) {
      bf16x8 pa[2], vb[8];
      #pragma unroll
      for (int mi = 0; mi < 2; mi++)
        pa[mi] = *(const bf16x8*)&Ps[qr + mi * 16 + l15][kk2 * 32 + quad * 8];
      #pragma unroll
      for (int di = 0; di < 8; di++)
        vb[di] = *(const bf16x8*)&Vs[di * 16 + l15][kk2 * 32 + quad * 8];
      #pragma unroll
      for (int mi = 0; mi < 2; mi++)
        #pragma unroll
        for (int di = 0; di < 8; di++)
          accO[mi][di] = __builtin_amdgcn_mfma_f32_16x16x32_bf16(pa[mi], vb[di], accO[mi][di], 0, 0, 0);
    }
  }
  if (SPLIT) {
    const size_t SP = (size_t)NH * SEQ * DH;
    const int sp = blockIdx.z;
    #pragma unroll
    for (int mi = 0; mi < 2; mi++)
      #pragma unroll
      for (int r = 0; r < 4; r++) {
        int gs = s0 + qr + mi * 16 + quad * 4 + r;
        size_t ib = sp * SP + ((size_t)h * SEQ + gs) * DH;
        if (l15 == 0) {
          Mp[(size_t)sp * NH * SEQ + h * SEQ + gs] = m_st[mi][r];
          Lp[(size_t)sp * NH * SEQ + h * SEQ + gs] = l_st[mi][r];
        }
        #pragma unroll
        for (int di = 0; di < 8; di++)
          Op[ib + di * 16 + l15] = accO[mi][di][r];
      }
  } else {
    #pragma unroll
    for (int mi = 0; mi < 2; mi++)
      #pragma unroll
      for (int r = 0; r < 4; r++) {
        float inv = 1.0f / l_st[mi][r];
        int gs = s0 + qr + mi * 16 + quad * 4 + r;
        #pragma unroll
        for (int di = 0; di < 8; di++)
          O[(size_t)gs * DM + h * DH + di * 16 + l15] = accO[mi][di][r] * inv;
      }
  }
}

// Merge NSPLIT partials + global absmax of result (feeds attn-out quant).
__global__ void flash_combine_k(const float* __restrict__ Op, const float* __restrict__ Mp,
                                const float* __restrict__ Lp, float* __restrict__ O,
                                unsigned* __restrict__ slot8) {
  const float fscale = 0.08838834764831845f * 1.4426950408889634f;
  const int t = threadIdx.x, lane = t & 63, w = t >> 6;   // 1024 thr, 16 waves
  const size_t SP = (size_t)NH * SEQ * DH, MR = (size_t)NH * SEQ;
  float lm = 0.f;
  for (int row = blockIdx.x * 16 + w; row < NH * SEQ; row += gridDim.x * 16) {
    float m0 = Mp[row], m1 = Mp[MR + row], m2 = Mp[2 * MR + row], m3 = Mp[3 * MR + row];
    float M = fmaxf(fmaxf(m0, m1), fmaxf(m2, m3));
    float w0 = exp2f((m0 - M) * fscale), w1 = exp2f((m1 - M) * fscale);
    float w2 = exp2f((m2 - M) * fscale), w3 = exp2f((m3 - M) * fscale);
    float inv = 1.0f / (Lp[row] * w0 + Lp[MR + row] * w1 + Lp[2 * MR + row] * w2 + Lp[3 * MR + row] * w3);
    int h = row / SEQ, s = row % SEQ;
    size_t ob = (size_t)s * DM + h * DH, ib = (size_t)row * DH;
    #pragma unroll
    for (int j = 0; j < 2; j++) {
      int d = lane + j * 64;
      float v = (Op[ib + d] * w0 + Op[SP + ib + d] * w1 +
                 Op[2 * SP + ib + d] * w2 + Op[3 * SP + ib + d] * w3) * inv;
      O[ob + d] = v;
      lm = fmaxf(lm, fabsf(v));
    }
  }
  lm = block_allmax_n(lm);
  if (t == 0) atomicMax(slot8, __float_as_uint(lm));
}

extern "C" void kernel_launch(void* const* d_in, const int* in_sizes, int n_in,
                              void* d_out, int out_size, void* d_ws, size_t ws_size,
                              hipStream_t stream) {
  (void)in_sizes; (void)n_in; (void)out_size;
  const void* hs   = d_in[0];
  const void* es   = d_in[1];
  const void* cosb = d_in[2];
  const void* sinb = d_in[3];
  const void* W[8]; const void* Bv[8];
  for (int i = 0; i < 8; i++) { W[i] = d_in[4 + 2 * i]; Bv[i] = d_in[5 + 2 * i]; }
  const void* nq  = d_in[20];
  const void* nk  = d_in[21];
  const void* naq = d_in[22];
  const void* nak = d_in[23];

  char* ws = (char*)d_ws;
  size_t off = 0;
  auto take = [&](size_t b) { char* p = ws + off; off += (b + 255) & ~(size_t)255; return p; };
  const size_t T = (size_t)NH * SEQ * DH * 4;      // 18.87 MB (one fp32 qkv tensor)

  unsigned* slots = (unsigned*)take(16 * SSTR * 4);   // 9 scale slots + flag, 128 B apart
  int* flagp = (int*)(slots + 15 * SSTR);
  float* wsc = (float*)take(8ull * DM * 4);

  // region gates (proven ws_size >= ~199 MB from round 4; full plan = ~191 MB)
  size_t here = off;
  size_t need_base  = 4 * T /*Oregion(split) or 3T used*/ + T /*attnf*/ + 3 * (T / 2) + 2 * ((size_t)NSPLIT * NH * SEQ * 4 + 256) + 1024;
  bool do_split = here + need_base <= ws_size;
  size_t region_sz = do_split ? 4 * T : 3 * T;

  char* region = take(region_sz);                  // qf,kf,vf; later Opart(+attnq)
  float* qf = (float*)region;
  float* kf = (float*)(region + T);
  float* vf = (float*)(region + 2 * T);
  float* Opart = (float*)region;
  __bf16* attnq = (__bf16*)region;                 // after combine (Opart dead)
  char* attnfR = take(T);                          // hq+eq early; attnf after flash
  __bf16* hq = (__bf16*)attnfR;
  __bf16* eq = (__bf16*)(attnfR + (size_t)L_IMG * DM * 2);
  float* attnf = (float*)attnfR;
  __bf16* qb  = (__bf16*)take(T / 2);
  __bf16* kb  = (__bf16*)take(T / 2);
  __bf16* vtb = (__bf16*)take(T / 2);
  float* Mpart = (float*)take((size_t)NSPLIT * NH * SEQ * 4);
  float* Lpart = (float*)take((size_t)NSPLIT * NH * SEQ * 4);
  bool do_prequant = (off + 8ull * DM * DM * 2 + 256 <= ws_size);
  __bf16* wq = do_prequant ? (__bf16*)take(8ull * DM * DM * 2) : nullptr;

  hipMemsetAsync(slots, 0, 16 * SSTR * 4, stream);
  detect_k<<<1, 64, 0, stream>>>(cosb, flagp);

  Ptrs8 win;
  for (int i = 0; i < 8; i++) win.p[i] = W[i];
  if (do_prequant)
    quant_weights_k<<<dim3(DM, 8), 256, 0, stream>>>(win, wq, wsc, flagp);
  else
    weight_scales_k<<<dim3(DM, 8), 256, 0, stream>>>(win, wsc, flagp);

  absmax_he_k<<<512, 256, 0, stream>>>(hs, es, slots, slots + SSTR, flagp);
  quant_he_k<<<1024, 256, 0, stream>>>(hs, es, slots, hq, eq, flagp);

  GemmArgs ga;
  ga.hq = hq; ga.eq = eq; ga.attnq = attnq; ga.wqp = wq;
  for (int i = 0; i < 8; i++) { ga.Wraw[i] = W[i]; ga.bias[i] = Bv[i]; }
  ga.wsc = wsc; ga.outs[0] = qf; ga.outs[1] = kf; ga.outs[2] = vf;
  ga.dout = d_out; ga.slots = slots; ga.flagp = flagp;

  if (do_prequant)
    gemm_f<0, 1><<<dim3(16, 18, 3), 256, 0, stream>>>(ga);
  else
    gemm_f<0, 0><<<dim3(16, 18, 3), 256, 0, stream>>>(ga);

  rms_absmax_v_k<<<256, 1024, 0, stream>>>(qf, kf, vf, nq, naq, nk, nak, slots, flagp);
  rope2_k<<<1024, 256, 0, stream>>>(qf, kf, cosb, sinb, slots, qb, kb, flagp);
  quant_transpose_v_k<<<dim3(SEQ / 64, DH / 64, NH), 256, 0, stream>>>(vf, slots, vtb);

  if (do_split) {
    flash_attn_k<1><<<dim3(SEQ / 128, NH, NSPLIT), 256, 0, stream>>>(qb, kb, vtb, nullptr,
                                                                     Opart, Mpart, Lpart);
    flash_combine_k<<<288, 1024, 0, stream>>>(Opart, Mpart, Lpart, attnf, slots + 8 * SSTR);
  } else {
    flash_attn_k<0><<<dim3(SEQ / 128, NH), 256, 0, stream>>>(qb, kb, vtb, attnf,
                                                             nullptr, nullptr, nullptr);
    absmax_f32_k<<<256, 256, 0, stream>>>(attnf, SEQ * DM, slots + 8 * SSTR);
  }
  quant_f32x8_k<<<1024, 256, 0, stream>>>(attnf, SEQ * DM / 8, slots + 8 * SSTR, attnq);

  if (do_prequant)
    gemm_f<1, 1><<<dim3(16, 18), 256, 0, stream>>>(ga);
  else
    gemm_f<1, 0><<<dim3(16, 18), 256, 0, stream>>>(ga);
}

// Round 6
// 691.423 us; speedup vs baseline: 3.5653x; 1.2007x over previous
//
#include <hip/hip_runtime.h>

// ===== Problem constants =====
constexpr int L_TXT = 256, L_IMG = 2048, SEQ = 2304;
constexpr int DM = 2048, NH = 16, DH = 128;
constexpr int NSPLIT = 4;      // flash split-K factor
constexpr int SSTR = 32;       // slot stride in unsigneds (128 B) - avoids atomic cacheline ping-pong

typedef __attribute__((ext_vector_type(8))) __bf16 bf16x8;
typedef __attribute__((ext_vector_type(4))) float f32x4;

// Runtime dtype flag: 0 = fp32 storage, 1 = bf16 (detected from rope_cos[0]).
__device__ __forceinline__ float ldin(const void* p, size_t i, int bf) {
  return bf ? (float)((const __bf16*)p)[i] : ((const float*)p)[i];
}
__device__ __forceinline__ float slot_scale(const unsigned* s) {
  return fmaxf(__uint_as_float(*s) / 127.0f, 1e-8f);
}
__device__ __forceinline__ float qclamp(float x, float sc) {
  float q = rintf(x / sc);     // RNE, matches jnp.round
  return fminf(fmaxf(q, -127.0f), 127.0f);
}
__device__ __forceinline__ float block_allmax_n(float v) {  // any blockDim multiple of 64 (<=1024)
  #pragma unroll
  for (int off = 32; off; off >>= 1) v = fmaxf(v, __shfl_xor(v, off));
  __shared__ float sm[16];
  int nw = blockDim.x >> 6;
  __syncthreads();
  if ((threadIdx.x & 63) == 0) sm[threadIdx.x >> 6] = v;
  __syncthreads();
  float m = sm[0];
  for (int i = 1; i < nw; i++) m = fmaxf(m, sm[i]);
  return m;
}

__global__ void detect_k(const void* cosp, int* flag) {
  if (threadIdx.x == 0) *flag = (((const unsigned short*)cosp)[0] != 0) ? 1 : 0;
}

struct Ptrs8 { const void* p[8]; };

// ===== Weight quantization (vectorized): scales + int-grid bf16 weights =====
__global__ void quant_weights_k(Ptrs8 win, __bf16* __restrict__ wq, float* __restrict__ scales,
                                const int* __restrict__ flagp) {
  const int bf = *flagp;
  int row = blockIdx.x, mat = blockIdx.y, t = threadIdx.x;
  float v[8];
  if (bf) {
    union { int4 q; __bf16 h[8]; } u;
    u.q = ((const int4*)((const __bf16*)win.p[mat] + (size_t)row * DM))[t];
    #pragma unroll
    for (int j = 0; j < 8; j++) v[j] = (float)u.h[j];
  } else {
    const float4* p = (const float4*)((const float*)win.p[mat] + (size_t)row * DM);
    float4 a = p[t * 2], b = p[t * 2 + 1];
    v[0]=a.x; v[1]=a.y; v[2]=a.z; v[3]=a.w; v[4]=b.x; v[5]=b.y; v[6]=b.z; v[7]=b.w;
  }
  float m = 0.f;
  #pragma unroll
  for (int j = 0; j < 8; j++) m = fmaxf(m, fabsf(v[j]));
  m = block_allmax_n(m);
  float sc = fmaxf(m / 127.0f, 1e-8f);
  if (t == 0) scales[mat * DM + row] = sc;
  union { int4 q; __bf16 h[8]; } o;
  #pragma unroll
  for (int j = 0; j < 8; j++) o.h[j] = (__bf16)qclamp(v[j], sc);
  ((int4*)(wq + (size_t)mat * DM * DM + (size_t)row * DM))[t] = o.q;
}
// fallback: scales only
__global__ void weight_scales_k(Ptrs8 win, float* __restrict__ scales, const int* __restrict__ flagp) {
  const int bf = *flagp;
  int row = blockIdx.x, mat = blockIdx.y, t = threadIdx.x;
  float m = 0.f;
  for (int c = t; c < DM; c += 256) m = fmaxf(m, fabsf(ldin(win.p[mat], (size_t)row * DM + c, bf)));
  m = block_allmax_n(m);
  if (t == 0) scales[mat * DM + row] = fmaxf(m / 127.0f, 1e-8f);
}

// ===== absmax of hidden + encoder in one pass (vectorized x8) =====
__global__ void absmax_he_k(const void* __restrict__ hs, const void* __restrict__ es,
                            unsigned* s0, unsigned* s1, const int* __restrict__ flagp) {
  const int bf = *flagp;
  const int n18 = L_IMG * DM / 8, n28 = L_TXT * DM / 8;
  float m1 = 0.f, m2 = 0.f;
  for (int i = blockIdx.x * 256 + threadIdx.x; i < n18 + n28; i += gridDim.x * 256) {
    bool h = i < n18;
    const void* src = h ? hs : es;
    int j = h ? i : i - n18;
    float lm = 0.f;
    if (bf) {
      union { int4 q; __bf16 x[8]; } u; u.q = ((const int4*)src)[j];
      #pragma unroll
      for (int k = 0; k < 8; k++) lm = fmaxf(lm, fabsf((float)u.x[k]));
    } else {
      const float4* p = (const float4*)src;
      float4 a = p[j * 2], b = p[j * 2 + 1];
      lm = fmaxf(fmaxf(fmaxf(fabsf(a.x), fabsf(a.y)), fmaxf(fabsf(a.z), fabsf(a.w))),
                 fmaxf(fmaxf(fabsf(b.x), fabsf(b.y)), fmaxf(fabsf(b.z), fabsf(b.w))));
    }
    if (h) m1 = fmaxf(m1, lm); else m2 = fmaxf(m2, lm);
  }
  m1 = block_allmax_n(m1);
  __syncthreads();
  m2 = block_allmax_n(m2);
  if (threadIdx.x == 0) { atomicMax(s0, __float_as_uint(m1)); atomicMax(s1, __float_as_uint(m2)); }
}

// ===== quantize hidden+encoder to int-grid bf16 (vectorized x8) =====
__global__ void quant_he_k(const void* __restrict__ hs, const void* __restrict__ es,
                           const unsigned* __restrict__ slots, __bf16* __restrict__ hqo,
                           __bf16* __restrict__ eqo, const int* __restrict__ flagp) {
  const int bf = *flagp;
  const int n18 = L_IMG * DM / 8, n28 = L_TXT * DM / 8;
  float sc0 = slot_scale(slots), sc1 = slot_scale(slots + SSTR);
  for (int i = blockIdx.x * 256 + threadIdx.x; i < n18 + n28; i += gridDim.x * 256) {
    bool h = i < n18;
    const void* src = h ? hs : es;
    int j = h ? i : i - n18;
    float sc = h ? sc0 : sc1;
    float v[8];
    if (bf) {
      union { int4 q; __bf16 x[8]; } u; u.q = ((const int4*)src)[j];
      #pragma unroll
      for (int k = 0; k < 8; k++) v[k] = (float)u.x[k];
    } else {
      const float4* p = (const float4*)src;
      float4 a = p[j * 2], b = p[j * 2 + 1];
      v[0]=a.x; v[1]=a.y; v[2]=a.z; v[3]=a.w; v[4]=b.x; v[5]=b.y; v[6]=b.z; v[7]=b.w;
    }
    union { int4 q; __bf16 x[8]; } o;
    #pragma unroll
    for (int k = 0; k < 8; k++) o.x[k] = (__bf16)qclamp(v[k], sc);
    ((int4*)(h ? hqo : eqo))[j] = o.q;
  }
}

// ===== quantize fp32 attn-out to int-grid bf16 (vectorized x8) =====
__global__ void quant_f32x8_k(const float* __restrict__ x, int n8,
                              const unsigned* __restrict__ slot, __bf16* __restrict__ out) {
  float sc = slot_scale(slot);
  for (int i = blockIdx.x * 256 + threadIdx.x; i < n8; i += gridDim.x * 256) {
    float4 a = ((const float4*)x)[i * 2], b = ((const float4*)x)[i * 2 + 1];
    union { int4 q; __bf16 h[8]; } o;
    o.h[0]=(__bf16)qclamp(a.x,sc); o.h[1]=(__bf16)qclamp(a.y,sc);
    o.h[2]=(__bf16)qclamp(a.z,sc); o.h[3]=(__bf16)qclamp(a.w,sc);
    o.h[4]=(__bf16)qclamp(b.x,sc); o.h[5]=(__bf16)qclamp(b.y,sc);
    o.h[6]=(__bf16)qclamp(b.z,sc); o.h[7]=(__bf16)qclamp(b.w,sc);
    ((int4*)out)[i] = o.q;
  }
}
// fallback absmax (non-split flash path)
__global__ void absmax_f32_k(const float* __restrict__ x, int n, unsigned* slot) {
  float m = 0.f;
  for (int i = blockIdx.x * 256 + threadIdx.x; i < n; i += gridDim.x * 256)
    m = fmaxf(m, fabsf(x[i]));
  m = block_allmax_n(m);
  if (threadIdx.x == 0) atomicMax(slot, __float_as_uint(m));
}

// ===== fused: rmsnorm(q)+absmax, rmsnorm(k)+absmax, absmax(v) =====
__global__ void rms_absmax_v_k(float* __restrict__ qf, float* __restrict__ kf, float* __restrict__ vf,
                               const void* nq, const void* naq, const void* nk, const void* nak,
                               unsigned* __restrict__ slots, const int* __restrict__ flagp) {
  const int bf = *flagp;
  const int t = threadIdx.x, lane = t & 63, wave = t >> 6;   // 1024 thr = 16 waves
  float wqt0 = ldin(naq, lane, bf), wqt1 = ldin(naq, lane + 64, bf);
  float wqi0 = ldin(nq,  lane, bf), wqi1 = ldin(nq,  lane + 64, bf);
  float wkt0 = ldin(nak, lane, bf), wkt1 = ldin(nak, lane + 64, bf);
  float wki0 = ldin(nk,  lane, bf), wki1 = ldin(nk,  lane + 64, bf);
  const int NR = NH * SEQ;
  float mx[6] = {0.f, 0.f, 0.f, 0.f, 0.f, 0.f};
  for (int row = blockIdx.x * 16 + wave; row < 3 * NR; row += gridDim.x * 16) {
    int tns = row / NR, r2 = row - tns * NR;
    int s = r2 % SEQ; bool txt = s < L_TXT;
    float* p = (tns == 0 ? qf : tns == 1 ? kf : vf) + (size_t)r2 * DH;
    float v0 = p[lane], v1 = p[lane + 64];
    if (tns < 2) {
      float ss = v0 * v0 + v1 * v1;
      #pragma unroll
      for (int off = 32; off; off >>= 1) ss += __shfl_xor(ss, off);
      float r = rsqrtf(ss * (1.0f / 128.0f) + 1e-6f);
      float w0, w1;
      if (tns == 0) { w0 = txt ? wqt0 : wqi0; w1 = txt ? wqt1 : wqi1; }
      else          { w0 = txt ? wkt0 : wki0; w1 = txt ? wkt1 : wki1; }
      v0 *= r * w0; v1 *= r * w1;
      p[lane] = v0; p[lane + 64] = v1;
    }
    int idx = tns * 2 + (txt ? 0 : 1);
    mx[idx] = fmaxf(mx[idx], fmaxf(fabsf(v0), fabsf(v1)));
  }
  #pragma unroll
  for (int off = 32; off; off >>= 1)
    #pragma unroll
    for (int j = 0; j < 6; j++) mx[j] = fmaxf(mx[j], __shfl_xor(mx[j], off));
  __shared__ float smx[16][6];
  if (lane == 0)
    #pragma unroll
    for (int j = 0; j < 6; j++) smx[wave][j] = mx[j];
  __syncthreads();
  if (t == 0) {
    #pragma unroll
    for (int j = 0; j < 6; j++) {
      float m = smx[0][j];
      for (int i = 1; i < 16; i++) m = fmaxf(m, smx[i][j]);
      atomicMax(slots + (2 + j) * SSTR, __float_as_uint(m));
    }
  }
}

// ===== fused rope for q and k: quantize (dequant) + rotate + bf16 =====
__global__ void rope2_k(const float* __restrict__ qf, const float* __restrict__ kf,
                        const void* cosb, const void* sinb, const unsigned* __restrict__ slots,
                        __bf16* __restrict__ qb, __bf16* __restrict__ kb, const int* __restrict__ flagp) {
  const int bf = *flagp;
  const int NP = NH * SEQ * 64;
  for (int i = blockIdx.x * 256 + threadIdx.x; i < 2 * NP; i += gridDim.x * 256) {
    int tns = i >= NP;
    int j = i - tns * NP;
    int pr = j & 63, rowg = j >> 6;
    int s = rowg % SEQ;
    const float* src = tns ? kf : qf;
    __bf16* dst = tns ? kb : qb;
    float sc = slot_scale(slots + (tns ? 4 : 2) * SSTR + (s < L_TXT ? 0 : SSTR));
    size_t base = (size_t)rowg * DH + pr * 2;
    float2 x2 = *(const float2*)(src + base);
    float q0 = qclamp(x2.x, sc) * sc, q1 = qclamp(x2.y, sc) * sc;
    float c0 = ldin(cosb, s * DH + 2 * pr, bf), c1 = ldin(cosb, s * DH + 2 * pr + 1, bf);
    float s0 = ldin(sinb, s * DH + 2 * pr, bf), s1 = ldin(sinb, s * DH + 2 * pr + 1, bf);
    dst[base]     = (__bf16)(q0 * c0 - q1 * s0);
    dst[base + 1] = (__bf16)(q1 * c1 + q0 * s1);
  }
}

// ===== V: quantize + transpose [NH][SEQ][DH] -> [NH][DH][SEQ] =====
__global__ void quant_transpose_v_k(const float* __restrict__ v, const unsigned* __restrict__ slots,
                                    __bf16* __restrict__ vt) {
  __shared__ float tile[64][65];
  int t = threadIdx.x;
  int s0 = blockIdx.x * 64, d0 = blockIdx.y * 64, h = blockIdx.z;
  #pragma unroll
  for (int i = 0; i < 16; i++) {
    int r = i * 4 + (t >> 6), c = t & 63;
    tile[r][c] = v[((size_t)(h * SEQ) + s0 + r) * DH + d0 + c];
  }
  __syncthreads();
  float sc = slot_scale(slots + (s0 < L_TXT ? 6 : 7) * SSTR);
  #pragma unroll
  for (int i = 0; i < 16; i++) {
    int d = i * 4 + (t >> 6), s = t & 63;
    float q = qclamp(tile[s][d], sc) * sc;
    vt[((size_t)(h * DH) + d0 + d) * SEQ + s0 + s] = (__bf16)q;
  }
}

// ===== GEMM (fused launches) =====
struct GemmArgs {
  const __bf16 *hq, *eq, *attnq;
  const __bf16* wqp;
  const void* Wraw[8];
  const float* wsc;
  const void* bias[8];
  float* outs[3];
  void* dout;
  const unsigned* slots;
  const int* flagp;
};
template<int MODE, int QW>
__global__ __launch_bounds__(256, 2)
void gemm_f(GemmArgs a) {
  const int bf = *a.flagp;
  constexpr int K = DM;
  __shared__ __bf16 As[128][72];
  __shared__ __bf16 Ws[128][72];
  const int t = threadIdx.x, lane = t & 63, wave = t >> 6;
  const int l15 = lane & 15, quad = lane >> 4;
  const int n0 = blockIdx.x * 128, y = blockIdx.y;
  int mat, outrow; const __bf16* A; const unsigned* aslot;
  if (MODE == 0) {
    bool txt = y < 2;
    mat = blockIdx.z + (txt ? 3 : 0);
    A = (txt ? a.eq : a.hq) + (size_t)(txt ? y * 128 : (y - 2) * 128) * K;
    outrow = y * 128;
    aslot = a.slots + (txt ? SSTR : 0);
  } else {
    bool img = y < 16;
    mat = img ? 6 : 7;
    A = a.attnq + (size_t)(img ? L_TXT + y * 128 : (y - 16) * 128) * K;
    outrow = img ? y * 128 : L_IMG + (y - 16) * 128;
    aslot = a.slots + 8 * SSTR;
  }
  const __bf16* Wq = QW ? a.wqp + (size_t)mat * DM * DM : nullptr;
  const void* Wr = a.Wraw[mat];
  const float* wrow = a.wsc + mat * DM;
  int wm = (wave & 1) * 64, wn = (wave >> 1) * 64;
  f32x4 acc[4][4] = {};
  int sr = t >> 3, sc = (t & 7) * 8;
  float wsc4[4];
  if (!QW) {
    #pragma unroll
    for (int p = 0; p < 4; p++) wsc4[p] = wrow[n0 + p * 32 + sr];
  }
  for (int k0 = 0; k0 < K; k0 += 64) {
    __syncthreads();
    #pragma unroll
    for (int p = 0; p < 4; p++) {
      int r = p * 32 + sr;
      *(int4*)&As[r][sc] = *(const int4*)&A[(size_t)r * K + k0 + sc];
      if (QW) {
        *(int4*)&Ws[r][sc] = *(const int4*)&Wq[(size_t)(n0 + r) * K + k0 + sc];
      } else {
        union { bf16x8 v; __bf16 h[8]; } q;
        if (bf) {
          union { int4 v; __bf16 h[8]; } u;
          u.v = *(const int4*)((const __bf16*)Wr + (size_t)(n0 + r) * K + k0 + sc);
          #pragma unroll
          for (int j = 0; j < 8; j++) q.h[j] = (__bf16)qclamp((float)u.h[j], wsc4[p]);
        } else {
          const float* wp = (const float*)Wr + (size_t)(n0 + r) * K + k0 + sc;
          float4 x = *(const float4*)wp, z = *(const float4*)(wp + 4);
          q.h[0]=(__bf16)qclamp(x.x,wsc4[p]); q.h[1]=(__bf16)qclamp(x.y,wsc4[p]);
          q.h[2]=(__bf16)qclamp(x.z,wsc4[p]); q.h[3]=(__bf16)qclamp(x.w,wsc4[p]);
          q.h[4]=(__bf16)qclamp(z.x,wsc4[p]); q.h[5]=(__bf16)qclamp(z.y,wsc4[p]);
          q.h[6]=(__bf16)qclamp(z.z,wsc4[p]); q.h[7]=(__bf16)qclamp(z.w,wsc4[p]);
        }
        *(bf16x8*)&Ws[r][sc] = q.v;
      }
    }
    __syncthreads();
    #pragma unroll
    for (int kk = 0; kk < 64; kk += 32) {
      bf16x8 af[4], bfr[4];
      #pragma unroll
      for (int i = 0; i < 4; i++) {
        af[i]  = *(const bf16x8*)&As[wm + i * 16 + l15][kk + quad * 8];
        bfr[i] = *(const bf16x8*)&Ws[wn + i * 16 + l15][kk + quad * 8];
      }
      #pragma unroll
      for (int i = 0; i < 4; i++)
        #pragma unroll
        for (int j = 0; j < 4; j++)
          acc[i][j] = __builtin_amdgcn_mfma_f32_16x16x32_bf16(af[i], bfr[j], acc[i][j], 0, 0, 0);
    }
  }
  float asc = slot_scale(aslot);
  #pragma unroll
  for (int j = 0; j < 4; j++) {
    int gn = n0 + wn + j * 16 + l15;
    float wsb = wrow[gn] * asc;
    float bv = ldin(a.bias[mat], gn, bf);
    #pragma unroll
    for (int i = 0; i < 4; i++)
      #pragma unroll
      for (int r = 0; r < 4; r++) {
        int gm = wm + i * 16 + quad * 4 + r;    // C/D: col=lane&15, row=quad*4+reg (m89)
        float val = acc[i][j][r] * wsb + bv;
        if (MODE == 0) {
          a.outs[blockIdx.z][(size_t)(gn >> 7) * (SEQ * DH) + (size_t)(outrow + gm) * DH + (gn & 127)] = val;
        } else {
          size_t idx = (size_t)(outrow + gm) * DM + gn;
          if (bf) ((__bf16*)a.dout)[idx] = (__bf16)val; else ((float*)a.dout)[idx] = val;
        }
      }
  }
}

// ===== Flash attention: Br=128, Bc=64, online softmax, Ps aliases Ks =====
// LDS 37888 B. __launch_bounds__(256,3): round-5's (256,4) capped unified V+A regs
// at 128/wave -> compiler spilled accumulators to scratch (measured: VGPR 104->64,
// HBM traffic 162 MB -> 1 GB, dur 186->320 us). 3 waves/EU budget = ~170 regs,
// fits the ~168 the kernel needs; LDS then allows 4 blocks/CU, regs give 3.
template<int SPLIT>
__global__ __launch_bounds__(256, 3)
void flash_attn_k(const __bf16* __restrict__ Qb, const __bf16* __restrict__ Kb,
                  const __bf16* __restrict__ Vt, float* __restrict__ O,
                  float* __restrict__ Op, float* __restrict__ Mp, float* __restrict__ Lp) {
  __shared__ __align__(16) char smem[19456 + 18432];
  auto Ks = (__bf16(*)[152])smem;            // 64 rows, stride 304 B (16-aligned)
  auto Ps = (__bf16(*)[72])smem;             // 128 rows, stride 144 B — aliases Ks
  auto Vs = (__bf16(*)[72])(smem + 19456);   // 128 rows [d][kc]
  const int t = threadIdx.x, lane = t & 63, wave = t >> 6;
  const int l15 = lane & 15, quad = lane >> 4;
  const int h = blockIdx.y, s0 = blockIdx.x * 128, qr = wave * 32;
  const float fscale = 0.08838834764831845f * 1.4426950408889634f;  // sm_scale*log2e

  bf16x8 qf[2][4];
  #pragma unroll
  for (int mi = 0; mi < 2; mi++)
    #pragma unroll
    for (int kk = 0; kk < 4; kk++)
      qf[mi][kk] = *(const bf16x8*)&Qb[(size_t)(h * SEQ + s0 + qr + mi * 16 + l15) * DH + kk * 32 + quad * 8];

  f32x4 accO[2][8] = {};
  float m_st[2][4], l_st[2][4];
  #pragma unroll
  for (int mi = 0; mi < 2; mi++)
    #pragma unroll
    for (int r = 0; r < 4; r++) { m_st[mi][r] = -1e30f; l_st[mi][r] = 0.f; }

  const int ktb = SPLIT ? blockIdx.z * (SEQ / 64 / NSPLIT) : 0;
  const int kte = SPLIT ? ktb + (SEQ / 64 / NSPLIT) : SEQ / 64;
  for (int kt = ktb; kt < kte; kt++) {
    __syncthreads();   // B1: prior PV reads of Vs/Ps done before restaging
    #pragma unroll
    for (int p = 0; p < 4; p++) {
      int r = p * 16 + (t >> 4), c = (t & 15) * 8;
      *(int4*)&Ks[r][c] = *(const int4*)&Kb[(size_t)(h * SEQ + kt * 64 + r) * DH + c];
    }
    #pragma unroll
    for (int p = 0; p < 4; p++) {
      int r = p * 32 + (t >> 3), c = (t & 7) * 8;
      *(int4*)&Vs[r][c] = *(const int4*)&Vt[(size_t)(h * DH + r) * SEQ + kt * 64 + c];
    }
    __syncthreads();   // B2: staging visible

    f32x4 accS[2][4] = {};
    #pragma unroll
    for (int kk = 0; kk < 4; kk++) {
      bf16x8 bk[4];
      #pragma unroll
      for (int ni = 0; ni < 4; ni++)
        bk[ni] = *(const bf16x8*)&Ks[ni * 16 + l15][kk * 32 + quad * 8];
      #pragma unroll
      for (int mi = 0; mi < 2; mi++)
        #pragma unroll
        for (int ni = 0; ni < 4; ni++)
          accS[mi][ni] = __builtin_amdgcn_mfma_f32_16x16x32_bf16(qf[mi][kk], bk[ni], accS[mi][ni], 0, 0, 0);
    }

    float al[2][4];
    #pragma unroll
    for (int mi = 0; mi < 2; mi++)
      #pragma unroll
      for (int r = 0; r < 4; r++) {
        float rm = fmaxf(fmaxf(accS[mi][0][r], accS[mi][1][r]), fmaxf(accS[mi][2][r], accS[mi][3][r]));
        #pragma unroll
        for (int off = 8; off > 0; off >>= 1) rm = fmaxf(rm, __shfl_xor(rm, off));
        float mn = fmaxf(m_st[mi][r], rm);
        al[mi][r] = exp2f((m_st[mi][r] - mn) * fscale);
        m_st[mi][r] = mn;
      }
    #pragma unroll
    for (int mi = 0; mi < 2; mi++)
      #pragma unroll
      for (int r = 0; r < 4; r++) {
        float rs = 0.f;
        #pragma unroll
        for (int ni = 0; ni < 4; ni++) {
          float pv = exp2f((accS[mi][ni][r] - m_st[mi][r]) * fscale);
          accS[mi][ni][r] = pv;
          rs += pv;
        }
        #pragma unroll
        for (int off = 8; off > 0; off >>= 1) rs += __shfl_xor(rs, off);
        l_st[mi][r] = l_st[mi][r] * al[mi][r] + rs;
      }
    #pragma unroll
    for (int mi = 0; mi < 2; mi++)
      #pragma unroll
      for (int di = 0; di < 8; di++)
        #pragma unroll
        for (int r = 0; r < 4; r++)
          accO[mi][di][r] *= al[mi][r];
    __syncthreads();   // B3: all waves' Ks reads done before P overwrites the alias
    #pragma unroll
    for (int mi = 0; mi < 2; mi++)
      #pragma unroll
      for (int ni = 0; ni < 4; ni++)
        #pragma unroll
        for (int r = 0; r < 4; r++)
          Ps[qr + mi * 16 + quad * 4 + r][ni * 16 + l15] = (__bf16)accS[mi][ni][r];
    // PV: Ps rows are wave-private (lgkmcnt handles RAW); Vs stable since B2
    #pragma unroll
    for (int kk2 = 0; kk2 < 2; kk2++) {
      bf16x8 pa[2], vb[8];
      #pragma unroll
      for (int mi = 0; mi < 2; mi++)
        pa[mi] = *(const bf16x8*)&Ps[qr + mi * 16 + l15][kk2 * 32 + quad * 8];
      #pragma unroll
      for (int di = 0; di < 8; di++)
        vb[di] = *(const bf16x8*)&Vs[di * 16 + l15][kk2 * 32 + quad * 8];
      #pragma unroll
      for (int mi = 0; mi < 2; mi++)
        #pragma unroll
        for (int di = 0; di < 8; di++)
          accO[mi][di] = __builtin_amdgcn_mfma_f32_16x16x32_bf16(pa[mi], vb[di], accO[mi][di], 0, 0, 0);
    }
  }
  if (SPLIT) {
    const size_t SP = (size_t)NH * SEQ * DH;
    const int sp = blockIdx.z;
    #pragma unroll
    for (int mi = 0; mi < 2; mi++)
      #pragma unroll
      for (int r = 0; r < 4; r++) {
        int gs = s0 + qr + mi * 16 + quad * 4 + r;
        size_t ib = sp * SP + ((size_t)h * SEQ + gs) * DH;
        if (l15 == 0) {
          Mp[(size_t)sp * NH * SEQ + h * SEQ + gs] = m_st[mi][r];
          Lp[(size_t)sp * NH * SEQ + h * SEQ + gs] = l_st[mi][r];
        }
        #pragma unroll
        for (int di = 0; di < 8; di++)
          Op[ib + di * 16 + l15] = accO[mi][di][r];
      }
  } else {
    #pragma unroll
    for (int mi = 0; mi < 2; mi++)
      #pragma unroll
      for (int r = 0; r < 4; r++) {
        float inv = 1.0f / l_st[mi][r];
        int gs = s0 + qr + mi * 16 + quad * 4 + r;
        #pragma unroll
        for (int di = 0; di < 8; di++)
          O[(size_t)gs * DM + h * DH + di * 16 + l15] = accO[mi][di][r] * inv;
      }
  }
}

// Merge NSPLIT partials + global absmax of result (feeds attn-out quant).
__global__ void flash_combine_k(const float* __restrict__ Op, const float* __restrict__ Mp,
                                const float* __restrict__ Lp, float* __restrict__ O,
                                unsigned* __restrict__ slot8) {
  const float fscale = 0.08838834764831845f * 1.4426950408889634f;
  const int t = threadIdx.x, lane = t & 63, w = t >> 6;   // 1024 thr, 16 waves
  const size_t SP = (size_t)NH * SEQ * DH, MR = (size_t)NH * SEQ;
  float lm = 0.f;
  for (int row = blockIdx.x * 16 + w; row < NH * SEQ; row += gridDim.x * 16) {
    float m0 = Mp[row], m1 = Mp[MR + row], m2 = Mp[2 * MR + row], m3 = Mp[3 * MR + row];
    float M = fmaxf(fmaxf(m0, m1), fmaxf(m2, m3));
    float w0 = exp2f((m0 - M) * fscale), w1 = exp2f((m1 - M) * fscale);
    float w2 = exp2f((m2 - M) * fscale), w3 = exp2f((m3 - M) * fscale);
    float inv = 1.0f / (Lp[row] * w0 + Lp[MR + row] * w1 + Lp[2 * MR + row] * w2 + Lp[3 * MR + row] * w3);
    int h = row / SEQ, s = row % SEQ;
    size_t ob = (size_t)s * DM + h * DH, ib = (size_t)row * DH;
    #pragma unroll
    for (int j = 0; j < 2; j++) {
      int d = lane + j * 64;
      float v = (Op[ib + d] * w0 + Op[SP + ib + d] * w1 +
                 Op[2 * SP + ib + d] * w2 + Op[3 * SP + ib + d] * w3) * inv;
      O[ob + d] = v;
      lm = fmaxf(lm, fabsf(v));
    }
  }
  lm = block_allmax_n(lm);
  if (t == 0) atomicMax(slot8, __float_as_uint(lm));
}

extern "C" void kernel_launch(void* const* d_in, const int* in_sizes, int n_in,
                              void* d_out, int out_size, void* d_ws, size_t ws_size,
                              hipStream_t stream) {
  (void)in_sizes; (void)n_in; (void)out_size;
  const void* hs   = d_in[0];
  const void* es   = d_in[1];
  const void* cosb = d_in[2];
  const void* sinb = d_in[3];
  const void* W[8]; const void* Bv[8];
  for (int i = 0; i < 8; i++) { W[i] = d_in[4 + 2 * i]; Bv[i] = d_in[5 + 2 * i]; }
  const void* nq  = d_in[20];
  const void* nk  = d_in[21];
  const void* naq = d_in[22];
  const void* nak = d_in[23];

  char* ws = (char*)d_ws;
  size_t off = 0;
  auto take = [&](size_t b) { char* p = ws + off; off += (b + 255) & ~(size_t)255; return p; };
  const size_t T = (size_t)NH * SEQ * DH * 4;      // 18.87 MB (one fp32 qkv tensor)

  unsigned* slots = (unsigned*)take(16 * SSTR * 4);   // 9 scale slots + flag, 128 B apart
  int* flagp = (int*)(slots + 15 * SSTR);
  float* wsc = (float*)take(8ull * DM * 4);

  size_t here = off;
  size_t need_base  = 4 * T + T + 3 * (T / 2) + 2 * ((size_t)NSPLIT * NH * SEQ * 4 + 256) + 1024;
  bool do_split = here + need_base <= ws_size;
  size_t region_sz = do_split ? 4 * T : 3 * T;

  char* region = take(region_sz);                  // qf,kf,vf; later Opart(+attnq)
  float* qf = (float*)region;
  float* kf = (float*)(region + T);
  float* vf = (float*)(region + 2 * T);
  float* Opart = (float*)region;
  __bf16* attnq = (__bf16*)region;                 // after combine (Opart dead)
  char* attnfR = take(T);                          // hq+eq early; attnf after flash
  __bf16* hq = (__bf16*)attnfR;
  __bf16* eq = (__bf16*)(attnfR + (size_t)L_IMG * DM * 2);
  float* attnf = (float*)attnfR;
  __bf16* qb  = (__bf16*)take(T / 2);
  __bf16* kb  = (__bf16*)take(T / 2);
  __bf16* vtb = (__bf16*)take(T / 2);
  float* Mpart = (float*)take((size_t)NSPLIT * NH * SEQ * 4);
  float* Lpart = (float*)take((size_t)NSPLIT * NH * SEQ * 4);
  bool do_prequant = (off + 8ull * DM * DM * 2 + 256 <= ws_size);
  __bf16* wq = do_prequant ? (__bf16*)take(8ull * DM * DM * 2) : nullptr;

  hipMemsetAsync(slots, 0, 16 * SSTR * 4, stream);
  detect_k<<<1, 64, 0, stream>>>(cosb, flagp);

  Ptrs8 win;
  for (int i = 0; i < 8; i++) win.p[i] = W[i];
  if (do_prequant)
    quant_weights_k<<<dim3(DM, 8), 256, 0, stream>>>(win, wq, wsc, flagp);
  else
    weight_scales_k<<<dim3(DM, 8), 256, 0, stream>>>(win, wsc, flagp);

  absmax_he_k<<<512, 256, 0, stream>>>(hs, es, slots, slots + SSTR, flagp);
  quant_he_k<<<1024, 256, 0, stream>>>(hs, es, slots, hq, eq, flagp);

  GemmArgs ga;
  ga.hq = hq; ga.eq = eq; ga.attnq = attnq; ga.wqp = wq;
  for (int i = 0; i < 8; i++) { ga.Wraw[i] = W[i]; ga.bias[i] = Bv[i]; }
  ga.wsc = wsc; ga.outs[0] = qf; ga.outs[1] = kf; ga.outs[2] = vf;
  ga.dout = d_out; ga.slots = slots; ga.flagp = flagp;

  if (do_prequant)
    gemm_f<0, 1><<<dim3(16, 18, 3), 256, 0, stream>>>(ga);
  else
    gemm_f<0, 0><<<dim3(16, 18, 3), 256, 0, stream>>>(ga);

  rms_absmax_v_k<<<256, 1024, 0, stream>>>(qf, kf, vf, nq, naq, nk, nak, slots, flagp);
  rope2_k<<<1024, 256, 0, stream>>>(qf, kf, cosb, sinb, slots, qb, kb, flagp);
  quant_transpose_v_k<<<dim3(SEQ / 64, DH / 64, NH), 256, 0, stream>>>(vf, slots, vtb);

  if (do_split) {
    flash_attn_k<1><<<dim3(SEQ / 128, NH, NSPLIT), 256, 0, stream>>>(qb, kb, vtb, nullptr,
                                                                     Opart, Mpart, Lpart);
    flash_combine_k<<<288, 1024, 0, stream>>>(Opart, Mpart, Lpart, attnf, slots + 8 * SSTR);
  } else {
    flash_attn_k<0><<<dim3(SEQ / 128, NH), 256, 0, stream>>>(qb, kb, vtb, attnf,
                                                             nullptr, nullptr, nullptr);
    absmax_f32_k<<<256, 256, 0, stream>>>(attnf, SEQ * DM, slots + 8 * SSTR);
  }
  quant_f32x8_k<<<1024, 256, 0, stream>>>(attnf, SEQ * DM / 8, slots + 8 * SSTR, attnq);

  if (do_prequant)
    gemm_f<1, 1><<<dim3(16, 18), 256, 0, stream>>>(ga);
  else
    gemm_f<1, 0><<<dim3(16, 18), 256, 0, stream>>>(ga);
}